// Round 6
// baseline (1550.813 us; speedup 1.0000x reference)
//
#include <hip/hip_runtime.h>
#include <math.h>

// ToxicityGATv2 — round 6: latency-pipelined aggregation. esrc preloaded into
// lane registers per node (one coalesced load), 4-edge chunks double-buffered
// (prefetch next chunk's eas+xl rows before computing current), masked tail,
// degree-sorted node order for wave load balance.

constexpr int N_ = 50000;
constexpr int E_ = 400000;
constexpr int G_ = 2000;
constexpr int H_ = 128;
constexpr int IN_ = 39;

// ---------------- bf16 pack/unpack (RNE) ----------------
__device__ __forceinline__ unsigned pk_bf16(float a, float b) {
  unsigned ua = __float_as_uint(a);
  unsigned ub = __float_as_uint(b);
  ua = (ua + 0x7fffu + ((ua >> 16) & 1u)) >> 16;
  ub = (ub + 0x7fffu + ((ub >> 16) & 1u)) & 0xffff0000u;
  return ua | ub;
}
__device__ __forceinline__ float up_lo(unsigned u) { return __uint_as_float(u << 16); }
__device__ __forceinline__ float up_hi(unsigned u) { return __uint_as_float(u & 0xffff0000u); }

// ---------------- histogram ----------------
__global__ __launch_bounds__(256) void hist_kernel(const int* __restrict__ keys, int n,
                                                   int* __restrict__ cnt) {
  for (int i = blockIdx.x * 256 + threadIdx.x; i < n; i += gridDim.x * 256)
    atomicAdd(&cnt[keys[i]], 1);
}

// ---------------- multi-block scan: local pass ----------------
__global__ __launch_bounds__(1024) void scan_local(const int* __restrict__ in,
                                                   int* __restrict__ outx,
                                                   int* __restrict__ bsum, int n) {
  __shared__ int wsum[16];
  int t = threadIdx.x, lane = t & 63, wid = t >> 6;
  int idx = blockIdx.x * 1024 + t;
  int v = (idx < n) ? in[idx] : 0;
  int x = v;
#pragma unroll
  for (int off = 1; off < 64; off <<= 1) {
    int y = __shfl_up(x, off, 64);
    if (lane >= off) x += y;
  }
  if (lane == 63) wsum[wid] = x;
  __syncthreads();
  if (t == 0) {
    int acc = 0;
#pragma unroll
    for (int w = 0; w < 16; w++) { int tmp = wsum[w]; wsum[w] = acc; acc += tmp; }
    bsum[blockIdx.x] = acc;
  }
  __syncthreads();
  if (idx < n) outx[idx] = wsum[wid] + x - v;
}

__global__ __launch_bounds__(64) void scan_bsum(const int* __restrict__ bsum,
                                                int* __restrict__ boff, int nb) {
  int t = threadIdx.x;
  int v = (t < nb) ? bsum[t] : 0;
  int x = v;
#pragma unroll
  for (int off = 1; off < 64; off <<= 1) {
    int y = __shfl_up(x, off, 64);
    if (t >= off) x += y;
  }
  boff[t] = x - v;  // exclusive
}

__global__ __launch_bounds__(1024) void scan_add(int* __restrict__ eoff,
                                                 const int* __restrict__ boff,
                                                 int* __restrict__ cursor, int n) {
  int idx = blockIdx.x * 1024 + threadIdx.x;
  if (idx < n) {
    int e = eoff[idx] + boff[idx >> 10];
    eoff[idx] = e;
    cursor[idx] = e;
  }
  if (idx == 0) eoff[n] = E_;
}

// ---------------- degree-bucket counting sort (64 buckets, cap 63) ----------------
__global__ __launch_bounds__(256) void deg_hist(const int* __restrict__ deg,
                                                int* __restrict__ dcnt) {
  int n = blockIdx.x * 256 + threadIdx.x;
  if (n < N_) atomicAdd(&dcnt[min(deg[n], 63)], 1);
}

__global__ __launch_bounds__(64) void deg_scan(const int* __restrict__ dcnt,
                                               int* __restrict__ dcur) {
  int t = threadIdx.x;
  int v = dcnt[t];
  int x = v;
#pragma unroll
  for (int off = 1; off < 64; off <<= 1) {
    int y = __shfl_up(x, off, 64);
    if (t >= off) x += y;
  }
  dcur[t] = x - v;
}

__global__ __launch_bounds__(256) void deg_scatter(const int* __restrict__ deg,
                                                   int* __restrict__ dcur,
                                                   int* __restrict__ order) {
  int n = blockIdx.x * 256 + threadIdx.x;
  if (n < N_) {
    int pos = atomicAdd(&dcur[min(deg[n], 63)], 1);
    order[pos] = n;
  }
}

// ---------------- goff directly from sorted batch ----------------
__global__ __launch_bounds__(256) void goff_from_sorted(const int* __restrict__ batch,
                                                        int* __restrict__ goff) {
  int i = blockIdx.x * 256 + threadIdx.x;
  if (i >= N_) return;
  int bi = batch[i];
  int bp = (i == 0) ? -1 : batch[i - 1];
  for (int g = bp + 1; g <= bi; g++) goff[g] = i;
  if (i == N_ - 1) {
    for (int g = bi + 1; g <= G_; g++) goff[g] = N_;
  }
}

// ---------------- edge scatter into dst-sorted order (bf16 attrs) ----------------
__global__ __launch_bounds__(256) void edge_scatter(const int* __restrict__ ei,
                                                    const float* __restrict__ ea,
                                                    int* __restrict__ cursor,
                                                    int* __restrict__ esrc,
                                                    unsigned* __restrict__ easb) {
  int e = blockIdx.x * 256 + threadIdx.x;
  if (e >= E_) return;
  int src = ei[e];
  int dst = ei[E_ + e];
  int j = atomicAdd(&cursor[dst], 1);
  esrc[j] = src;
  const float4* eav = (const float4*)(ea + (size_t)e * 8);
  float4 a0 = eav[0], a1 = eav[1];
  uint4 o;
  o.x = pk_bf16(a0.x, a0.y);
  o.y = pk_bf16(a0.z, a0.w);
  o.z = pk_bf16(a1.x, a1.y);
  o.w = pk_bf16(a1.z, a1.w);
  ((uint4*)easb)[j] = o;
}

// ---------------- input GEMM + fused colstats ----------------
__global__ __launch_bounds__(256) void in_gemm(const float* __restrict__ x,
                                               const float* __restrict__ W,
                                               const float* __restrict__ b,
                                               float* __restrict__ y,
                                               float* __restrict__ ssum,
                                               float* __restrict__ ssq) {
  __shared__ float xs[32][40];
  __shared__ float s1[256], s2[256];
  int t = threadIdx.x;
  int row0 = blockIdx.x * 32;
  for (int i = t; i < 32 * IN_; i += 256) {
    int r = i / IN_, k = i % IN_;
    int row = row0 + r;
    xs[r][k] = (row < N_) ? x[row * IN_ + k] : 0.f;
  }
  __syncthreads();
  int col = t & 127;
  int half = t >> 7;
  float acc[16];
#pragma unroll
  for (int r = 0; r < 16; r++) acc[r] = 0.f;
  for (int k = 0; k < IN_; k++) {
    float w = W[k * H_ + col];
#pragma unroll
    for (int r = 0; r < 16; r++) acc[r] = fmaf(xs[half * 16 + r][k], w, acc[r]);
  }
  float bb = b[col];
  float a1 = 0.f, a2 = 0.f;
#pragma unroll
  for (int r = 0; r < 16; r++) {
    int row = row0 + half * 16 + r;
    float v = acc[r] + bb;
    if (row < N_) {
      y[row * H_ + col] = v;
      a1 += v;
      a2 = fmaf(v, v, a2);
    }
  }
  s1[t] = a1; s2[t] = a2;
  __syncthreads();
  if (t < 128) {
    atomicAdd(&ssum[t], s1[t] + s1[t + 128]);
    atomicAdd(&ssq[t], s2[t] + s2[t + 128]);
  }
}

// ---------------- node GEMM with fused BN epilogue; bf16 packed outputs --------
template <int MODE>
__global__ __launch_bounds__(256) void gemm_xlxr(const float* __restrict__ xn_ro,
                                                 float* __restrict__ xn,
                                                 const float* __restrict__ buf,
                                                 const float* __restrict__ g,
                                                 const float* __restrict__ beta,
                                                 const float* __restrict__ mean,
                                                 const float* __restrict__ rstd,
                                                 const float* __restrict__ Wlp,
                                                 const float* __restrict__ Wrp,
                                                 unsigned* __restrict__ xlb,
                                                 unsigned* __restrict__ xrb) {
  __shared__ float xs[64][16];
  __shared__ float wl_s[16][128];
  __shared__ float wr_s[16][128];
  int t = threadIdx.x;
  int tx = t & 31;
  int ty = t >> 5;
  int row0 = blockIdx.x * 64;
  float4 accl[8], accr[8];
#pragma unroll
  for (int r = 0; r < 8; r++) {
    accl[r] = make_float4(0.f, 0.f, 0.f, 0.f);
    accr[r] = make_float4(0.f, 0.f, 0.f, 0.f);
  }
  for (int kc = 0; kc < H_; kc += 16) {
    __syncthreads();
    {
      int r = t >> 2;
      int k4 = (t & 3) * 4;
      int row = row0 + r;
      int c = kc + k4;
      float4 v = make_float4(0.f, 0.f, 0.f, 0.f);
      if (row < N_) {
        if (MODE == 0) {
          v = *(const float4*)&xn_ro[row * H_ + c];
        } else {
          float4 bv = *(const float4*)&buf[row * H_ + c];
          float4 gv = *(const float4*)&g[c];
          float4 be = *(const float4*)&beta[c];
          float4 mn = *(const float4*)&mean[c];
          float4 rs = *(const float4*)&rstd[c];
          float t0 = gv.x * (bv.x - mn.x) * rs.x + be.x;
          float t1 = gv.y * (bv.y - mn.y) * rs.y + be.y;
          float t2 = gv.z * (bv.z - mn.z) * rs.z + be.z;
          float t3 = gv.w * (bv.w - mn.w) * rs.w + be.w;
          if (MODE == 1) {
            v = make_float4(fmaxf(t0, 0.f), fmaxf(t1, 0.f), fmaxf(t2, 0.f), fmaxf(t3, 0.f));
          } else {
            float4 xo = *(const float4*)&xn[row * H_ + c];
            v.x = xo.x + ((t0 > 0.f) ? t0 : (__expf(t0) - 1.f));
            v.y = xo.y + ((t1 > 0.f) ? t1 : (__expf(t1) - 1.f));
            v.z = xo.z + ((t2 > 0.f) ? t2 : (__expf(t2) - 1.f));
            v.w = xo.w + ((t3 > 0.f) ? t3 : (__expf(t3) - 1.f));
          }
          *(float4*)&xn[row * H_ + c] = v;
        }
      }
      *(float4*)&xs[r][k4] = v;
    }
    for (int i = t; i < 512; i += 256) {
      int k = i >> 5;
      int c4 = (i & 31) * 4;
      *(float4*)&wl_s[k][c4] = *(const float4*)&Wlp[(kc + k) * H_ + c4];
      *(float4*)&wr_s[k][c4] = *(const float4*)&Wrp[(kc + k) * H_ + c4];
    }
    __syncthreads();
#pragma unroll
    for (int k = 0; k < 16; k += 4) {
      float4 xv[8];
#pragma unroll
      for (int r = 0; r < 8; r++) xv[r] = *(const float4*)&xs[ty * 8 + r][k];
#pragma unroll
      for (int kk = 0; kk < 4; kk++) {
        float4 wl = *(const float4*)&wl_s[k + kk][tx * 4];
        float4 wr = *(const float4*)&wr_s[k + kk][tx * 4];
#pragma unroll
        for (int r = 0; r < 8; r++) {
          float xvr = (kk == 0) ? xv[r].x : (kk == 1) ? xv[r].y : (kk == 2) ? xv[r].z : xv[r].w;
          accl[r].x = fmaf(xvr, wl.x, accl[r].x);
          accl[r].y = fmaf(xvr, wl.y, accl[r].y);
          accl[r].z = fmaf(xvr, wl.z, accl[r].z);
          accl[r].w = fmaf(xvr, wl.w, accl[r].w);
          accr[r].x = fmaf(xvr, wr.x, accr[r].x);
          accr[r].y = fmaf(xvr, wr.y, accr[r].y);
          accr[r].z = fmaf(xvr, wr.z, accr[r].z);
          accr[r].w = fmaf(xvr, wr.w, accr[r].w);
        }
      }
    }
  }
#pragma unroll
  for (int r = 0; r < 8; r++) {
    int row = row0 + ty * 8 + r;
    if (row < N_) {
      uint2 ul, ur;
      ul.x = pk_bf16(accl[r].x, accl[r].y);
      ul.y = pk_bf16(accl[r].z, accl[r].w);
      ur.x = pk_bf16(accr[r].x, accr[r].y);
      ur.y = pk_bf16(accr[r].z, accr[r].w);
      *(uint2*)&xlb[(size_t)row * 64 + tx * 2] = ul;
      *(uint2*)&xrb[(size_t)row * 64 + tx * 2] = ur;
    }
  }
}

// ---------------- CSR aggregation: pipelined, esrc-in-registers --------------
__device__ __forceinline__ float ep8u(const uint4& u, const float* w) {
  float ep = up_lo(u.x) * w[0];
  ep = fmaf(up_hi(u.x), w[1], ep);
  ep = fmaf(up_lo(u.y), w[2], ep);
  ep = fmaf(up_hi(u.y), w[3], ep);
  ep = fmaf(up_lo(u.z), w[4], ep);
  ep = fmaf(up_hi(u.z), w[5], ep);
  ep = fmaf(up_lo(u.w), w[6], ep);
  ep = fmaf(up_hi(u.w), w[7], ep);
  return ep;
}

__global__ __launch_bounds__(256, 5) void agg_csr(const int* __restrict__ order,
                                                  const int* __restrict__ eoff,
                                                  const int* __restrict__ esrc,
                                                  const unsigned* __restrict__ easb,
                                                  const float* __restrict__ Wel,
                                                  const float* __restrict__ attl,
                                                  const unsigned* __restrict__ xlb,
                                                  const unsigned* __restrict__ xrb,
                                                  const float* __restrict__ cb,
                                                  float* __restrict__ buf,
                                                  float* __restrict__ ssum,
                                                  float* __restrict__ ssq) {
  __shared__ float sA[256], sB[256], sC[256], sD[256];
  int t = threadIdx.x;
  int l = t & 63;
  int sub = t >> 6;
  int c0 = l * 2;
  float w0[8], w1[8];
#pragma unroll
  for (int k = 0; k < 8; k++) {
    float2 wv = *(const float2*)&Wel[k * H_ + c0];
    w0[k] = wv.x; w1[k] = wv.y;
  }
  float2 attv = *(const float2*)&attl[c0];
  float2 cbv = *(const float2*)&cb[c0];
  const uint4* eas4 = (const uint4*)easb;
  float a1_0 = 0.f, a1_1 = 0.f, a2_0 = 0.f, a2_1 = 0.f;
  int stride = gridDim.x * 4;
  for (int idx = blockIdx.x * 4 + sub; idx < N_; idx += stride) {
    int n = order[idx];
    unsigned xru = xrb[(size_t)n * 64 + l];
    float xr0 = up_lo(xru), xr1 = up_hi(xru);
    int e0 = eoff[n];
    int deg = eoff[n + 1] - e0;
    float acc0 = 0.f, acc1 = 0.f, den = 0.f;
    if (deg > 0 && deg <= 64) {
      int s_all = (l < deg) ? esrc[e0 + l] : 0;
      int C = (deg + 3) >> 2;
      unsigned cx0, cx1, cx2, cx3;
      uint4 cu0, cu1, cu2, cu3;
      {
        int s0 = __shfl(s_all, 0, 64), s1 = __shfl(s_all, 1, 64);
        int s2 = __shfl(s_all, 2, 64), s3 = __shfl(s_all, 3, 64);
        cu0 = eas4[e0 + 0]; cu1 = eas4[e0 + 1];
        cu2 = eas4[e0 + 2]; cu3 = eas4[e0 + 3];
        cx0 = xlb[(size_t)s0 * 64 + l]; cx1 = xlb[(size_t)s1 * 64 + l];
        cx2 = xlb[(size_t)s2 * 64 + l]; cx3 = xlb[(size_t)s3 * 64 + l];
      }
      for (int c = 0; c < C; c++) {
        unsigned nx0 = 0, nx1 = 0, nx2 = 0, nx3 = 0;
        uint4 nu0 = make_uint4(0, 0, 0, 0), nu1 = nu0, nu2 = nu0, nu3 = nu0;
        if (c + 1 < C) {
          int jb = (c + 1) * 4;
          int s0 = __shfl(s_all, jb + 0, 64), s1 = __shfl(s_all, jb + 1, 64);
          int s2 = __shfl(s_all, jb + 2, 64), s3 = __shfl(s_all, jb + 3, 64);
          nu0 = eas4[e0 + jb + 0]; nu1 = eas4[e0 + jb + 1];
          nu2 = eas4[e0 + jb + 2]; nu3 = eas4[e0 + jb + 3];
          nx0 = xlb[(size_t)s0 * 64 + l]; nx1 = xlb[(size_t)s1 * 64 + l];
          nx2 = xlb[(size_t)s2 * 64 + l]; nx3 = xlb[(size_t)s3 * 64 + l];
        }
        int jb = c * 4;
        float x00 = up_lo(cx0), x01 = up_hi(cx0);
        float x10 = up_lo(cx1), x11 = up_hi(cx1);
        float x20 = up_lo(cx2), x21 = up_hi(cx2);
        float x30 = up_lo(cx3), x31 = up_hi(cx3);
        float m00 = x00 + xr0 + ep8u(cu0, w0);
        float m01 = x01 + xr1 + ep8u(cu0, w1);
        float m10 = x10 + xr0 + ep8u(cu1, w0);
        float m11 = x11 + xr1 + ep8u(cu1, w1);
        float m20 = x20 + xr0 + ep8u(cu2, w0);
        float m21 = x21 + xr1 + ep8u(cu2, w1);
        float m30 = x30 + xr0 + ep8u(cu3, w0);
        float m31 = x31 + xr1 + ep8u(cu3, w1);
        m00 = (m00 > 0.f) ? m00 : 0.2f * m00;
        m01 = (m01 > 0.f) ? m01 : 0.2f * m01;
        m10 = (m10 > 0.f) ? m10 : 0.2f * m10;
        m11 = (m11 > 0.f) ? m11 : 0.2f * m11;
        m20 = (m20 > 0.f) ? m20 : 0.2f * m20;
        m21 = (m21 > 0.f) ? m21 : 0.2f * m21;
        m30 = (m30 > 0.f) ? m30 : 0.2f * m30;
        m31 = (m31 > 0.f) ? m31 : 0.2f * m31;
        float p0 = fmaf(m00, attv.x, m01 * attv.y);
        float p1 = fmaf(m10, attv.x, m11 * attv.y);
        float p2 = fmaf(m20, attv.x, m21 * attv.y);
        float p3 = fmaf(m30, attv.x, m31 * attv.y);
#pragma unroll
        for (int off = 8; off > 0; off >>= 1) {
          p0 += __shfl_xor(p0, off, 64);
          p1 += __shfl_xor(p1, off, 64);
          p2 += __shfl_xor(p2, off, 64);
          p3 += __shfl_xor(p3, off, 64);
        }
        float e0v = (jb + 0 < deg) ? __expf(p0) : 0.f;
        float e1v = (jb + 1 < deg) ? __expf(p1) : 0.f;
        float e2v = (jb + 2 < deg) ? __expf(p2) : 0.f;
        float e3v = (jb + 3 < deg) ? __expf(p3) : 0.f;
        acc0 = fmaf(e0v, x00, acc0); acc1 = fmaf(e0v, x01, acc1);
        acc0 = fmaf(e1v, x10, acc0); acc1 = fmaf(e1v, x11, acc1);
        acc0 = fmaf(e2v, x20, acc0); acc1 = fmaf(e2v, x21, acc1);
        acc0 = fmaf(e3v, x30, acc0); acc1 = fmaf(e3v, x31, acc1);
        den += (e0v + e1v) + (e2v + e3v);
        cx0 = nx0; cx1 = nx1; cx2 = nx2; cx3 = nx3;
        cu0 = nu0; cu1 = nu1; cu2 = nu2; cu3 = nu3;
      }
    } else if (deg > 64) {
      for (int j = e0; j < e0 + deg; j++) {
        int s0 = esrc[j];
        uint4 u0 = eas4[j];
        unsigned xu0 = xlb[(size_t)s0 * 64 + l];
        float x00 = up_lo(xu0), x01 = up_hi(xu0);
        float m00 = x00 + xr0 + ep8u(u0, w0);
        float m01 = x01 + xr1 + ep8u(u0, w1);
        m00 = (m00 > 0.f) ? m00 : 0.2f * m00;
        m01 = (m01 > 0.f) ? m01 : 0.2f * m01;
        float p0 = fmaf(m00, attv.x, m01 * attv.y);
#pragma unroll
        for (int off = 8; off > 0; off >>= 1) p0 += __shfl_xor(p0, off, 64);
        float e0v = __expf(p0);
        acc0 = fmaf(e0v, x00, acc0);
        acc1 = fmaf(e0v, x01, acc1);
        den += e0v;
      }
    }
    float inv = 1.f / (den + 1e-16f);
    float h0 = acc0 * inv + cbv.x;
    float h1 = acc1 * inv + cbv.y;
    *(float2*)&buf[(size_t)n * H_ + c0] = make_float2(h0, h1);
    a1_0 += h0; a1_1 += h1;
    a2_0 = fmaf(h0, h0, a2_0); a2_1 = fmaf(h1, h1, a2_1);
  }
  sA[t] = a1_0; sB[t] = a1_1; sC[t] = a2_0; sD[t] = a2_1;
  __syncthreads();
  if (t < 64) {
    float r1 = sA[t] + sA[t + 64] + sA[t + 128] + sA[t + 192];
    float r2 = sB[t] + sB[t + 64] + sB[t + 128] + sB[t + 192];
    float r3 = sC[t] + sC[t + 64] + sC[t + 128] + sC[t + 192];
    float r4 = sD[t] + sD[t + 64] + sD[t + 128] + sD[t + 192];
    atomicAdd(&ssum[2 * t], r1);
    atomicAdd(&ssum[2 * t + 1], r2);
    atomicAdd(&ssq[2 * t], r3);
    atomicAdd(&ssq[2 * t + 1], r4);
  }
}

// ---------------- bn_final (always cleans all 256 slots) ----------------
__global__ void bn_final(float* __restrict__ ssum, float* __restrict__ ssq, float rows_inv,
                         int cols, float* __restrict__ mean, float* __restrict__ rstd) {
  int c = threadIdx.x;
  if (c < cols) {
    float m = ssum[c] * rows_inv;
    float v = ssq[c] * rows_inv - m * m;
    mean[c] = m;
    rstd[c] = rsqrtf(v + 1e-5f);
  }
  ssum[c] = 0.f;
  ssq[c] = 0.f;
}

__global__ __launch_bounds__(256) void apply_bn_relu(const float* __restrict__ y,
                                                     float* __restrict__ out,
                                                     const float* __restrict__ g,
                                                     const float* __restrict__ beta,
                                                     const float* __restrict__ mean,
                                                     const float* __restrict__ rstd,
                                                     long total, int cmask) {
  long i = (long)blockIdx.x * 256 + threadIdx.x;
  if (i >= total) return;
  int c = (int)i & cmask;
  float v = g[c] * (y[i] - mean[c]) * rstd[c] + beta[c];
  out[i] = fmaxf(v, 0.f);
}

// ---------------- pooling with fused layer-2 residual ----------------
__global__ __launch_bounds__(128) void pool_residual(const int* __restrict__ goff,
                                                     const float* __restrict__ xn,
                                                     const float* __restrict__ buf,
                                                     const float* __restrict__ g,
                                                     const float* __restrict__ beta,
                                                     const float* __restrict__ mean,
                                                     const float* __restrict__ rstd,
                                                     float* __restrict__ xg) {
  int gr = blockIdx.x;
  int t = threadIdx.x;
  int n0 = goff[gr], n1 = goff[gr + 1];
  float gg = g[t], bb = beta[t], mm = mean[t], rr = rstd[t];
  float s = 0.f, mx = -INFINITY;
  for (int n = n0; n < n1; n++) {
    float w = gg * (buf[(size_t)n * H_ + t] - mm) * rr + bb;
    w = (w > 0.f) ? w : (__expf(w) - 1.f);
    float v = xn[(size_t)n * H_ + t] + w;
    s += v;
    mx = fmaxf(mx, v);
  }
  float c = (float)(n1 - n0);
  xg[gr * 384 + t] = s / fmaxf(c, 1.f);
  xg[gr * 384 + 128 + t] = (c > 0.f) ? mx : 0.f;
  xg[gr * 384 + 256 + t] = s;
}

// ---------------- MLP GEMMs (fused colstats) ----------------
template <int K, int COLS>
__global__ void mlp_gemm(const float* __restrict__ A, const float* __restrict__ W,
                         const float* __restrict__ b, float* __restrict__ Y, int rows,
                         float* __restrict__ ssum, float* __restrict__ ssq) {
  __shared__ float xs[8][K];
  int t = threadIdx.x;
  int row0 = blockIdx.x * 8;
  for (int i = t; i < 8 * K; i += COLS) {
    int r = i / K, k = i % K;
    int row = row0 + r;
    xs[r][k] = (row < rows) ? A[row * K + k] : 0.f;
  }
  __syncthreads();
  float acc[8];
#pragma unroll
  for (int r = 0; r < 8; r++) acc[r] = 0.f;
  for (int k = 0; k < K; k++) {
    float w = W[k * COLS + t];
#pragma unroll
    for (int r = 0; r < 8; r++) acc[r] = fmaf(xs[r][k], w, acc[r]);
  }
  float bb = b[t];
  float a1 = 0.f, a2 = 0.f;
#pragma unroll
  for (int r = 0; r < 8; r++) {
    int row = row0 + r;
    if (row < rows) {
      float v = acc[r] + bb;
      Y[row * COLS + t] = v;
      a1 += v;
      a2 = fmaf(v, v, a2);
    }
  }
  atomicAdd(&ssum[t], a1);
  atomicAdd(&ssq[t], a2);
}

// ---------------- head ----------------
__global__ __launch_bounds__(64) void head_kernel(const float* __restrict__ u,
                                                  const float* __restrict__ W,
                                                  const float* __restrict__ b,
                                                  float* __restrict__ out) {
  __shared__ float row[128];
  int g = blockIdx.x;
  int t = threadIdx.x;
  row[t] = u[g * 128 + t];
  row[t + 64] = u[g * 128 + 64 + t];
  __syncthreads();
  if (t < 12) {
    float acc = b[t];
    for (int k = 0; k < 128; k++) acc = fmaf(row[k], W[k * 12 + t], acc);
    out[g * 12 + t] = 1.f / (1.f + expf(-acc));
  }
}

// ---------------- launcher ----------------
extern "C" void kernel_launch(void* const* d_in, const int* in_sizes, int n_in, void* d_out,
                              int out_size, void* d_ws, size_t ws_size, hipStream_t stream) {
  (void)in_sizes; (void)n_in; (void)out_size; (void)ws_size;
  const float* x       = (const float*)d_in[0];
  const int*   ei      = (const int*)d_in[1];
  const float* ea      = (const float*)d_in[2];
  const int*   batch   = (const int*)d_in[3];
  const float* in_W    = (const float*)d_in[4];
  const float* in_b    = (const float*)d_in[5];
  const float* in_g    = (const float*)d_in[6];
  const float* in_beta = (const float*)d_in[7];
  const float* Wl      = (const float*)d_in[8];
  const float* Wr      = (const float*)d_in[9];
  const float* We      = (const float*)d_in[10];
  const float* att     = (const float*)d_in[11];
  const float* conv_b  = (const float*)d_in[12];
  const float* bn_g    = (const float*)d_in[13];
  const float* bn_b    = (const float*)d_in[14];
  const float* t1_W    = (const float*)d_in[15];
  const float* t1_b    = (const float*)d_in[16];
  const float* t1_g    = (const float*)d_in[17];
  const float* t1_beta = (const float*)d_in[18];
  const float* t2_W    = (const float*)d_in[19];
  const float* t2_b    = (const float*)d_in[20];
  const float* t2_g    = (const float*)d_in[21];
  const float* t2_beta = (const float*)d_in[22];
  const float* head_W  = (const float*)d_in[23];
  const float* head_b  = (const float*)d_in[24];
  float* out = (float*)d_out;

  float* p = (float*)d_ws;
  float* xn   = p; p += N_ * H_;
  float* buf  = p; p += N_ * H_;
  float* ssum = p; p += 256;
  float* ssq  = p; p += 256;   // contiguous after ssum (joint memset)
  float* mean = p; p += 256;
  float* rstd = p; p += 256;
  float* xg   = p; p += G_ * 384;
  float* u1   = p; p += G_ * 256;
  float* u2   = p; p += G_ * 128;
  unsigned* up = (unsigned*)p;
  unsigned* xlb  = up; up += (size_t)N_ * 64;
  unsigned* xrb  = up; up += (size_t)N_ * 64;
  unsigned* easb = up; up += (size_t)E_ * 4 + 16;  // +4 uint4 pad for masked tail loads
  int* ip = (int*)up;
  int* deg    = ip; ip += N_;
  int* dcnt   = ip; ip += 64;   // contiguous after deg: joint memset
  int* eoff   = ip; ip += N_ + 1;
  int* cursor = ip; ip += N_;
  int* goff   = ip; ip += G_ + 1;
  int* esrc   = ip; ip += E_;
  int* bsum   = ip; ip += 64;
  int* boff   = ip; ip += 64;
  int* dcur   = ip; ip += 64;
  int* order  = ip; ip += N_;

  // ---- build CSR structures + degree-sorted node order ----
  hipMemsetAsync(deg, 0, (size_t)(N_ + 64) * sizeof(int), stream);
  hist_kernel<<<1024, 256, 0, stream>>>(ei + E_, E_, deg);
  scan_local<<<49, 1024, 0, stream>>>(deg, eoff, bsum, N_);
  scan_bsum<<<1, 64, 0, stream>>>(bsum, boff, 49);
  scan_add<<<49, 1024, 0, stream>>>(eoff, boff, cursor, N_);
  deg_hist<<<(N_ + 255) / 256, 256, 0, stream>>>(deg, dcnt);
  deg_scan<<<1, 64, 0, stream>>>(dcnt, dcur);
  deg_scatter<<<(N_ + 255) / 256, 256, 0, stream>>>(deg, dcur, order);
  edge_scatter<<<(E_ + 255) / 256, 256, 0, stream>>>(ei, ea, cursor, esrc, easb);
  goff_from_sorted<<<(N_ + 255) / 256, 256, 0, stream>>>(batch, goff);

  // ---- input layer ----
  hipMemsetAsync(ssum, 0, 512 * sizeof(float), stream);
  in_gemm<<<(N_ + 31) / 32, 256, 0, stream>>>(x, in_W, in_b, buf, ssum, ssq);
  bn_final<<<1, 256, 0, stream>>>(ssum, ssq, 1.f / N_, H_, mean, rstd);

  // ---- 3 GATv2 layers ----
  for (int l = 0; l < 3; l++) {
    if (l == 0) {
      gemm_xlxr<1><<<(N_ + 63) / 64, 256, 0, stream>>>(xn, xn, buf, in_g, in_beta, mean, rstd,
                                                       Wl + l * H_ * H_, Wr + l * H_ * H_,
                                                       xlb, xrb);
    } else {
      gemm_xlxr<2><<<(N_ + 63) / 64, 256, 0, stream>>>(xn, xn, buf, bn_g + (l - 1) * H_,
                                                       bn_b + (l - 1) * H_, mean, rstd,
                                                       Wl + l * H_ * H_, Wr + l * H_ * H_,
                                                       xlb, xrb);
    }
    agg_csr<<<1280, 256, 0, stream>>>(order, eoff, esrc, easb, We + l * 8 * H_, att + l * H_,
                                      xlb, xrb, conv_b + l * H_, buf, ssum, ssq);
    bn_final<<<1, 256, 0, stream>>>(ssum, ssq, 1.f / N_, H_, mean, rstd);
  }

  // ---- pooling with fused layer-2 residual ----
  pool_residual<<<G_, 128, 0, stream>>>(goff, xn, buf, bn_g + 2 * H_, bn_b + 2 * H_,
                                        mean, rstd, xg);

  // ---- t1 ----
  mlp_gemm<384, 256><<<G_ / 8, 256, 0, stream>>>(xg, t1_W, t1_b, u1, G_, ssum, ssq);
  bn_final<<<1, 256, 0, stream>>>(ssum, ssq, 1.f / G_, 256, mean, rstd);
  apply_bn_relu<<<(G_ * 256 + 255) / 256, 256, 0, stream>>>(u1, u1, t1_g, t1_beta, mean, rstd,
                                                            (long)G_ * 256, 255);

  // ---- t2 ----
  mlp_gemm<256, 128><<<G_ / 8, 128, 0, stream>>>(u1, t2_W, t2_b, u2, G_, ssum, ssq);
  bn_final<<<1, 256, 0, stream>>>(ssum, ssq, 1.f / G_, 128, mean, rstd);
  apply_bn_relu<<<(G_ * 128 + 255) / 256, 256, 0, stream>>>(u2, u2, t2_g, t2_beta, mean, rstd,
                                                            (long)G_ * 128, 127);

  // ---- head ----
  head_kernel<<<G_, 64, 0, stream>>>(u2, head_W, head_b, out);
}

// Round 7
// 1240.061 us; speedup vs baseline: 1.2506x; 1.2506x over previous
//
#include <hip/hip_runtime.h>
#include <math.h>

// ToxicityGATv2 — round 7: round-6 pipelined aggregation with the VGPR cap
// REMOVED (launch_bounds(256,5) caused ~480 MB of scratch spill traffic and a
// 2x regression). Plain 256 bounds; grid back to 2048.

constexpr int N_ = 50000;
constexpr int E_ = 400000;
constexpr int G_ = 2000;
constexpr int H_ = 128;
constexpr int IN_ = 39;

// ---------------- bf16 pack/unpack (RNE) ----------------
__device__ __forceinline__ unsigned pk_bf16(float a, float b) {
  unsigned ua = __float_as_uint(a);
  unsigned ub = __float_as_uint(b);
  ua = (ua + 0x7fffu + ((ua >> 16) & 1u)) >> 16;
  ub = (ub + 0x7fffu + ((ub >> 16) & 1u)) & 0xffff0000u;
  return ua | ub;
}
__device__ __forceinline__ float up_lo(unsigned u) { return __uint_as_float(u << 16); }
__device__ __forceinline__ float up_hi(unsigned u) { return __uint_as_float(u & 0xffff0000u); }

// ---------------- histogram ----------------
__global__ __launch_bounds__(256) void hist_kernel(const int* __restrict__ keys, int n,
                                                   int* __restrict__ cnt) {
  for (int i = blockIdx.x * 256 + threadIdx.x; i < n; i += gridDim.x * 256)
    atomicAdd(&cnt[keys[i]], 1);
}

// ---------------- multi-block scan: local pass ----------------
__global__ __launch_bounds__(1024) void scan_local(const int* __restrict__ in,
                                                   int* __restrict__ outx,
                                                   int* __restrict__ bsum, int n) {
  __shared__ int wsum[16];
  int t = threadIdx.x, lane = t & 63, wid = t >> 6;
  int idx = blockIdx.x * 1024 + t;
  int v = (idx < n) ? in[idx] : 0;
  int x = v;
#pragma unroll
  for (int off = 1; off < 64; off <<= 1) {
    int y = __shfl_up(x, off, 64);
    if (lane >= off) x += y;
  }
  if (lane == 63) wsum[wid] = x;
  __syncthreads();
  if (t == 0) {
    int acc = 0;
#pragma unroll
    for (int w = 0; w < 16; w++) { int tmp = wsum[w]; wsum[w] = acc; acc += tmp; }
    bsum[blockIdx.x] = acc;
  }
  __syncthreads();
  if (idx < n) outx[idx] = wsum[wid] + x - v;
}

__global__ __launch_bounds__(64) void scan_bsum(const int* __restrict__ bsum,
                                                int* __restrict__ boff, int nb) {
  int t = threadIdx.x;
  int v = (t < nb) ? bsum[t] : 0;
  int x = v;
#pragma unroll
  for (int off = 1; off < 64; off <<= 1) {
    int y = __shfl_up(x, off, 64);
    if (t >= off) x += y;
  }
  boff[t] = x - v;  // exclusive
}

__global__ __launch_bounds__(1024) void scan_add(int* __restrict__ eoff,
                                                 const int* __restrict__ boff,
                                                 int* __restrict__ cursor, int n) {
  int idx = blockIdx.x * 1024 + threadIdx.x;
  if (idx < n) {
    int e = eoff[idx] + boff[idx >> 10];
    eoff[idx] = e;
    cursor[idx] = e;
  }
  if (idx == 0) eoff[n] = E_;
}

// ---------------- degree-bucket counting sort (64 buckets, cap 63) ----------------
__global__ __launch_bounds__(256) void deg_hist(const int* __restrict__ deg,
                                                int* __restrict__ dcnt) {
  int n = blockIdx.x * 256 + threadIdx.x;
  if (n < N_) atomicAdd(&dcnt[min(deg[n], 63)], 1);
}

__global__ __launch_bounds__(64) void deg_scan(const int* __restrict__ dcnt,
                                               int* __restrict__ dcur) {
  int t = threadIdx.x;
  int v = dcnt[t];
  int x = v;
#pragma unroll
  for (int off = 1; off < 64; off <<= 1) {
    int y = __shfl_up(x, off, 64);
    if (t >= off) x += y;
  }
  dcur[t] = x - v;
}

__global__ __launch_bounds__(256) void deg_scatter(const int* __restrict__ deg,
                                                   int* __restrict__ dcur,
                                                   int* __restrict__ order) {
  int n = blockIdx.x * 256 + threadIdx.x;
  if (n < N_) {
    int pos = atomicAdd(&dcur[min(deg[n], 63)], 1);
    order[pos] = n;
  }
}

// ---------------- goff directly from sorted batch ----------------
__global__ __launch_bounds__(256) void goff_from_sorted(const int* __restrict__ batch,
                                                        int* __restrict__ goff) {
  int i = blockIdx.x * 256 + threadIdx.x;
  if (i >= N_) return;
  int bi = batch[i];
  int bp = (i == 0) ? -1 : batch[i - 1];
  for (int g = bp + 1; g <= bi; g++) goff[g] = i;
  if (i == N_ - 1) {
    for (int g = bi + 1; g <= G_; g++) goff[g] = N_;
  }
}

// ---------------- edge scatter into dst-sorted order (bf16 attrs) ----------------
__global__ __launch_bounds__(256) void edge_scatter(const int* __restrict__ ei,
                                                    const float* __restrict__ ea,
                                                    int* __restrict__ cursor,
                                                    int* __restrict__ esrc,
                                                    unsigned* __restrict__ easb) {
  int e = blockIdx.x * 256 + threadIdx.x;
  if (e >= E_) return;
  int src = ei[e];
  int dst = ei[E_ + e];
  int j = atomicAdd(&cursor[dst], 1);
  esrc[j] = src;
  const float4* eav = (const float4*)(ea + (size_t)e * 8);
  float4 a0 = eav[0], a1 = eav[1];
  uint4 o;
  o.x = pk_bf16(a0.x, a0.y);
  o.y = pk_bf16(a0.z, a0.w);
  o.z = pk_bf16(a1.x, a1.y);
  o.w = pk_bf16(a1.z, a1.w);
  ((uint4*)easb)[j] = o;
}

// ---------------- input GEMM + fused colstats ----------------
__global__ __launch_bounds__(256) void in_gemm(const float* __restrict__ x,
                                               const float* __restrict__ W,
                                               const float* __restrict__ b,
                                               float* __restrict__ y,
                                               float* __restrict__ ssum,
                                               float* __restrict__ ssq) {
  __shared__ float xs[32][40];
  __shared__ float s1[256], s2[256];
  int t = threadIdx.x;
  int row0 = blockIdx.x * 32;
  for (int i = t; i < 32 * IN_; i += 256) {
    int r = i / IN_, k = i % IN_;
    int row = row0 + r;
    xs[r][k] = (row < N_) ? x[row * IN_ + k] : 0.f;
  }
  __syncthreads();
  int col = t & 127;
  int half = t >> 7;
  float acc[16];
#pragma unroll
  for (int r = 0; r < 16; r++) acc[r] = 0.f;
  for (int k = 0; k < IN_; k++) {
    float w = W[k * H_ + col];
#pragma unroll
    for (int r = 0; r < 16; r++) acc[r] = fmaf(xs[half * 16 + r][k], w, acc[r]);
  }
  float bb = b[col];
  float a1 = 0.f, a2 = 0.f;
#pragma unroll
  for (int r = 0; r < 16; r++) {
    int row = row0 + half * 16 + r;
    float v = acc[r] + bb;
    if (row < N_) {
      y[row * H_ + col] = v;
      a1 += v;
      a2 = fmaf(v, v, a2);
    }
  }
  s1[t] = a1; s2[t] = a2;
  __syncthreads();
  if (t < 128) {
    atomicAdd(&ssum[t], s1[t] + s1[t + 128]);
    atomicAdd(&ssq[t], s2[t] + s2[t + 128]);
  }
}

// ---------------- node GEMM with fused BN epilogue; bf16 packed outputs --------
template <int MODE>
__global__ __launch_bounds__(256) void gemm_xlxr(const float* __restrict__ xn_ro,
                                                 float* __restrict__ xn,
                                                 const float* __restrict__ buf,
                                                 const float* __restrict__ g,
                                                 const float* __restrict__ beta,
                                                 const float* __restrict__ mean,
                                                 const float* __restrict__ rstd,
                                                 const float* __restrict__ Wlp,
                                                 const float* __restrict__ Wrp,
                                                 unsigned* __restrict__ xlb,
                                                 unsigned* __restrict__ xrb) {
  __shared__ float xs[64][16];
  __shared__ float wl_s[16][128];
  __shared__ float wr_s[16][128];
  int t = threadIdx.x;
  int tx = t & 31;
  int ty = t >> 5;
  int row0 = blockIdx.x * 64;
  float4 accl[8], accr[8];
#pragma unroll
  for (int r = 0; r < 8; r++) {
    accl[r] = make_float4(0.f, 0.f, 0.f, 0.f);
    accr[r] = make_float4(0.f, 0.f, 0.f, 0.f);
  }
  for (int kc = 0; kc < H_; kc += 16) {
    __syncthreads();
    {
      int r = t >> 2;
      int k4 = (t & 3) * 4;
      int row = row0 + r;
      int c = kc + k4;
      float4 v = make_float4(0.f, 0.f, 0.f, 0.f);
      if (row < N_) {
        if (MODE == 0) {
          v = *(const float4*)&xn_ro[row * H_ + c];
        } else {
          float4 bv = *(const float4*)&buf[row * H_ + c];
          float4 gv = *(const float4*)&g[c];
          float4 be = *(const float4*)&beta[c];
          float4 mn = *(const float4*)&mean[c];
          float4 rs = *(const float4*)&rstd[c];
          float t0 = gv.x * (bv.x - mn.x) * rs.x + be.x;
          float t1 = gv.y * (bv.y - mn.y) * rs.y + be.y;
          float t2 = gv.z * (bv.z - mn.z) * rs.z + be.z;
          float t3 = gv.w * (bv.w - mn.w) * rs.w + be.w;
          if (MODE == 1) {
            v = make_float4(fmaxf(t0, 0.f), fmaxf(t1, 0.f), fmaxf(t2, 0.f), fmaxf(t3, 0.f));
          } else {
            float4 xo = *(const float4*)&xn[row * H_ + c];
            v.x = xo.x + ((t0 > 0.f) ? t0 : (__expf(t0) - 1.f));
            v.y = xo.y + ((t1 > 0.f) ? t1 : (__expf(t1) - 1.f));
            v.z = xo.z + ((t2 > 0.f) ? t2 : (__expf(t2) - 1.f));
            v.w = xo.w + ((t3 > 0.f) ? t3 : (__expf(t3) - 1.f));
          }
          *(float4*)&xn[row * H_ + c] = v;
        }
      }
      *(float4*)&xs[r][k4] = v;
    }
    for (int i = t; i < 512; i += 256) {
      int k = i >> 5;
      int c4 = (i & 31) * 4;
      *(float4*)&wl_s[k][c4] = *(const float4*)&Wlp[(kc + k) * H_ + c4];
      *(float4*)&wr_s[k][c4] = *(const float4*)&Wrp[(kc + k) * H_ + c4];
    }
    __syncthreads();
#pragma unroll
    for (int k = 0; k < 16; k += 4) {
      float4 xv[8];
#pragma unroll
      for (int r = 0; r < 8; r++) xv[r] = *(const float4*)&xs[ty * 8 + r][k];
#pragma unroll
      for (int kk = 0; kk < 4; kk++) {
        float4 wl = *(const float4*)&wl_s[k + kk][tx * 4];
        float4 wr = *(const float4*)&wr_s[k + kk][tx * 4];
#pragma unroll
        for (int r = 0; r < 8; r++) {
          float xvr = (kk == 0) ? xv[r].x : (kk == 1) ? xv[r].y : (kk == 2) ? xv[r].z : xv[r].w;
          accl[r].x = fmaf(xvr, wl.x, accl[r].x);
          accl[r].y = fmaf(xvr, wl.y, accl[r].y);
          accl[r].z = fmaf(xvr, wl.z, accl[r].z);
          accl[r].w = fmaf(xvr, wl.w, accl[r].w);
          accr[r].x = fmaf(xvr, wr.x, accr[r].x);
          accr[r].y = fmaf(xvr, wr.y, accr[r].y);
          accr[r].z = fmaf(xvr, wr.z, accr[r].z);
          accr[r].w = fmaf(xvr, wr.w, accr[r].w);
        }
      }
    }
  }
#pragma unroll
  for (int r = 0; r < 8; r++) {
    int row = row0 + ty * 8 + r;
    if (row < N_) {
      uint2 ul, ur;
      ul.x = pk_bf16(accl[r].x, accl[r].y);
      ul.y = pk_bf16(accl[r].z, accl[r].w);
      ur.x = pk_bf16(accr[r].x, accr[r].y);
      ur.y = pk_bf16(accr[r].z, accr[r].w);
      *(uint2*)&xlb[(size_t)row * 64 + tx * 2] = ul;
      *(uint2*)&xrb[(size_t)row * 64 + tx * 2] = ur;
    }
  }
}

// ---------------- CSR aggregation: pipelined, esrc-in-registers --------------
__device__ __forceinline__ float ep8u(const uint4& u, const float* w) {
  float ep = up_lo(u.x) * w[0];
  ep = fmaf(up_hi(u.x), w[1], ep);
  ep = fmaf(up_lo(u.y), w[2], ep);
  ep = fmaf(up_hi(u.y), w[3], ep);
  ep = fmaf(up_lo(u.z), w[4], ep);
  ep = fmaf(up_hi(u.z), w[5], ep);
  ep = fmaf(up_lo(u.w), w[6], ep);
  ep = fmaf(up_hi(u.w), w[7], ep);
  return ep;
}

__global__ __launch_bounds__(256) void agg_csr(const int* __restrict__ order,
                                               const int* __restrict__ eoff,
                                               const int* __restrict__ esrc,
                                               const unsigned* __restrict__ easb,
                                               const float* __restrict__ Wel,
                                               const float* __restrict__ attl,
                                               const unsigned* __restrict__ xlb,
                                               const unsigned* __restrict__ xrb,
                                               const float* __restrict__ cb,
                                               float* __restrict__ buf,
                                               float* __restrict__ ssum,
                                               float* __restrict__ ssq) {
  __shared__ float sA[256], sB[256], sC[256], sD[256];
  int t = threadIdx.x;
  int l = t & 63;
  int sub = t >> 6;
  int c0 = l * 2;
  float w0[8], w1[8];
#pragma unroll
  for (int k = 0; k < 8; k++) {
    float2 wv = *(const float2*)&Wel[k * H_ + c0];
    w0[k] = wv.x; w1[k] = wv.y;
  }
  float2 attv = *(const float2*)&attl[c0];
  float2 cbv = *(const float2*)&cb[c0];
  const uint4* eas4 = (const uint4*)easb;
  float a1_0 = 0.f, a1_1 = 0.f, a2_0 = 0.f, a2_1 = 0.f;
  int stride = gridDim.x * 4;
  for (int idx = blockIdx.x * 4 + sub; idx < N_; idx += stride) {
    int n = order[idx];
    unsigned xru = xrb[(size_t)n * 64 + l];
    float xr0 = up_lo(xru), xr1 = up_hi(xru);
    int e0 = eoff[n];
    int deg = eoff[n + 1] - e0;
    float acc0 = 0.f, acc1 = 0.f, den = 0.f;
    if (deg > 0 && deg <= 64) {
      int s_all = (l < deg) ? esrc[e0 + l] : 0;
      int C = (deg + 3) >> 2;
      unsigned cx0, cx1, cx2, cx3;
      uint4 cu0, cu1, cu2, cu3;
      {
        int s0 = __shfl(s_all, 0, 64), s1 = __shfl(s_all, 1, 64);
        int s2 = __shfl(s_all, 2, 64), s3 = __shfl(s_all, 3, 64);
        cu0 = eas4[e0 + 0]; cu1 = eas4[e0 + 1];
        cu2 = eas4[e0 + 2]; cu3 = eas4[e0 + 3];
        cx0 = xlb[(size_t)s0 * 64 + l]; cx1 = xlb[(size_t)s1 * 64 + l];
        cx2 = xlb[(size_t)s2 * 64 + l]; cx3 = xlb[(size_t)s3 * 64 + l];
      }
      for (int c = 0; c < C; c++) {
        unsigned nx0 = 0, nx1 = 0, nx2 = 0, nx3 = 0;
        uint4 nu0 = make_uint4(0, 0, 0, 0), nu1 = nu0, nu2 = nu0, nu3 = nu0;
        if (c + 1 < C) {
          int jb = (c + 1) * 4;
          int s0 = __shfl(s_all, jb + 0, 64), s1 = __shfl(s_all, jb + 1, 64);
          int s2 = __shfl(s_all, jb + 2, 64), s3 = __shfl(s_all, jb + 3, 64);
          nu0 = eas4[e0 + jb + 0]; nu1 = eas4[e0 + jb + 1];
          nu2 = eas4[e0 + jb + 2]; nu3 = eas4[e0 + jb + 3];
          nx0 = xlb[(size_t)s0 * 64 + l]; nx1 = xlb[(size_t)s1 * 64 + l];
          nx2 = xlb[(size_t)s2 * 64 + l]; nx3 = xlb[(size_t)s3 * 64 + l];
        }
        int jb = c * 4;
        float x00 = up_lo(cx0), x01 = up_hi(cx0);
        float x10 = up_lo(cx1), x11 = up_hi(cx1);
        float x20 = up_lo(cx2), x21 = up_hi(cx2);
        float x30 = up_lo(cx3), x31 = up_hi(cx3);
        float m00 = x00 + xr0 + ep8u(cu0, w0);
        float m01 = x01 + xr1 + ep8u(cu0, w1);
        float m10 = x10 + xr0 + ep8u(cu1, w0);
        float m11 = x11 + xr1 + ep8u(cu1, w1);
        float m20 = x20 + xr0 + ep8u(cu2, w0);
        float m21 = x21 + xr1 + ep8u(cu2, w1);
        float m30 = x30 + xr0 + ep8u(cu3, w0);
        float m31 = x31 + xr1 + ep8u(cu3, w1);
        m00 = (m00 > 0.f) ? m00 : 0.2f * m00;
        m01 = (m01 > 0.f) ? m01 : 0.2f * m01;
        m10 = (m10 > 0.f) ? m10 : 0.2f * m10;
        m11 = (m11 > 0.f) ? m11 : 0.2f * m11;
        m20 = (m20 > 0.f) ? m20 : 0.2f * m20;
        m21 = (m21 > 0.f) ? m21 : 0.2f * m21;
        m30 = (m30 > 0.f) ? m30 : 0.2f * m30;
        m31 = (m31 > 0.f) ? m31 : 0.2f * m31;
        float p0 = fmaf(m00, attv.x, m01 * attv.y);
        float p1 = fmaf(m10, attv.x, m11 * attv.y);
        float p2 = fmaf(m20, attv.x, m21 * attv.y);
        float p3 = fmaf(m30, attv.x, m31 * attv.y);
#pragma unroll
        for (int off = 8; off > 0; off >>= 1) {
          p0 += __shfl_xor(p0, off, 64);
          p1 += __shfl_xor(p1, off, 64);
          p2 += __shfl_xor(p2, off, 64);
          p3 += __shfl_xor(p3, off, 64);
        }
        float e0v = (jb + 0 < deg) ? __expf(p0) : 0.f;
        float e1v = (jb + 1 < deg) ? __expf(p1) : 0.f;
        float e2v = (jb + 2 < deg) ? __expf(p2) : 0.f;
        float e3v = (jb + 3 < deg) ? __expf(p3) : 0.f;
        acc0 = fmaf(e0v, x00, acc0); acc1 = fmaf(e0v, x01, acc1);
        acc0 = fmaf(e1v, x10, acc0); acc1 = fmaf(e1v, x11, acc1);
        acc0 = fmaf(e2v, x20, acc0); acc1 = fmaf(e2v, x21, acc1);
        acc0 = fmaf(e3v, x30, acc0); acc1 = fmaf(e3v, x31, acc1);
        den += (e0v + e1v) + (e2v + e3v);
        cx0 = nx0; cx1 = nx1; cx2 = nx2; cx3 = nx3;
        cu0 = nu0; cu1 = nu1; cu2 = nu2; cu3 = nu3;
      }
    } else if (deg > 64) {
      for (int j = e0; j < e0 + deg; j++) {
        int s0 = esrc[j];
        uint4 u0 = eas4[j];
        unsigned xu0 = xlb[(size_t)s0 * 64 + l];
        float x00 = up_lo(xu0), x01 = up_hi(xu0);
        float m00 = x00 + xr0 + ep8u(u0, w0);
        float m01 = x01 + xr1 + ep8u(u0, w1);
        m00 = (m00 > 0.f) ? m00 : 0.2f * m00;
        m01 = (m01 > 0.f) ? m01 : 0.2f * m01;
        float p0 = fmaf(m00, attv.x, m01 * attv.y);
#pragma unroll
        for (int off = 8; off > 0; off >>= 1) p0 += __shfl_xor(p0, off, 64);
        float e0v = __expf(p0);
        acc0 = fmaf(e0v, x00, acc0);
        acc1 = fmaf(e0v, x01, acc1);
        den += e0v;
      }
    }
    float inv = 1.f / (den + 1e-16f);
    float h0 = acc0 * inv + cbv.x;
    float h1 = acc1 * inv + cbv.y;
    *(float2*)&buf[(size_t)n * H_ + c0] = make_float2(h0, h1);
    a1_0 += h0; a1_1 += h1;
    a2_0 = fmaf(h0, h0, a2_0); a2_1 = fmaf(h1, h1, a2_1);
  }
  sA[t] = a1_0; sB[t] = a1_1; sC[t] = a2_0; sD[t] = a2_1;
  __syncthreads();
  if (t < 64) {
    float r1 = sA[t] + sA[t + 64] + sA[t + 128] + sA[t + 192];
    float r2 = sB[t] + sB[t + 64] + sB[t + 128] + sB[t + 192];
    float r3 = sC[t] + sC[t + 64] + sC[t + 128] + sC[t + 192];
    float r4 = sD[t] + sD[t + 64] + sD[t + 128] + sD[t + 192];
    atomicAdd(&ssum[2 * t], r1);
    atomicAdd(&ssum[2 * t + 1], r2);
    atomicAdd(&ssq[2 * t], r3);
    atomicAdd(&ssq[2 * t + 1], r4);
  }
}

// ---------------- bn_final (always cleans all 256 slots) ----------------
__global__ void bn_final(float* __restrict__ ssum, float* __restrict__ ssq, float rows_inv,
                         int cols, float* __restrict__ mean, float* __restrict__ rstd) {
  int c = threadIdx.x;
  if (c < cols) {
    float m = ssum[c] * rows_inv;
    float v = ssq[c] * rows_inv - m * m;
    mean[c] = m;
    rstd[c] = rsqrtf(v + 1e-5f);
  }
  ssum[c] = 0.f;
  ssq[c] = 0.f;
}

__global__ __launch_bounds__(256) void apply_bn_relu(const float* __restrict__ y,
                                                     float* __restrict__ out,
                                                     const float* __restrict__ g,
                                                     const float* __restrict__ beta,
                                                     const float* __restrict__ mean,
                                                     const float* __restrict__ rstd,
                                                     long total, int cmask) {
  long i = (long)blockIdx.x * 256 + threadIdx.x;
  if (i >= total) return;
  int c = (int)i & cmask;
  float v = g[c] * (y[i] - mean[c]) * rstd[c] + beta[c];
  out[i] = fmaxf(v, 0.f);
}

// ---------------- pooling with fused layer-2 residual ----------------
__global__ __launch_bounds__(128) void pool_residual(const int* __restrict__ goff,
                                                     const float* __restrict__ xn,
                                                     const float* __restrict__ buf,
                                                     const float* __restrict__ g,
                                                     const float* __restrict__ beta,
                                                     const float* __restrict__ mean,
                                                     const float* __restrict__ rstd,
                                                     float* __restrict__ xg) {
  int gr = blockIdx.x;
  int t = threadIdx.x;
  int n0 = goff[gr], n1 = goff[gr + 1];
  float gg = g[t], bb = beta[t], mm = mean[t], rr = rstd[t];
  float s = 0.f, mx = -INFINITY;
  for (int n = n0; n < n1; n++) {
    float w = gg * (buf[(size_t)n * H_ + t] - mm) * rr + bb;
    w = (w > 0.f) ? w : (__expf(w) - 1.f);
    float v = xn[(size_t)n * H_ + t] + w;
    s += v;
    mx = fmaxf(mx, v);
  }
  float c = (float)(n1 - n0);
  xg[gr * 384 + t] = s / fmaxf(c, 1.f);
  xg[gr * 384 + 128 + t] = (c > 0.f) ? mx : 0.f;
  xg[gr * 384 + 256 + t] = s;
}

// ---------------- MLP GEMMs (fused colstats) ----------------
template <int K, int COLS>
__global__ void mlp_gemm(const float* __restrict__ A, const float* __restrict__ W,
                         const float* __restrict__ b, float* __restrict__ Y, int rows,
                         float* __restrict__ ssum, float* __restrict__ ssq) {
  __shared__ float xs[8][K];
  int t = threadIdx.x;
  int row0 = blockIdx.x * 8;
  for (int i = t; i < 8 * K; i += COLS) {
    int r = i / K, k = i % K;
    int row = row0 + r;
    xs[r][k] = (row < rows) ? A[row * K + k] : 0.f;
  }
  __syncthreads();
  float acc[8];
#pragma unroll
  for (int r = 0; r < 8; r++) acc[r] = 0.f;
  for (int k = 0; k < K; k++) {
    float w = W[k * COLS + t];
#pragma unroll
    for (int r = 0; r < 8; r++) acc[r] = fmaf(xs[r][k], w, acc[r]);
  }
  float bb = b[t];
  float a1 = 0.f, a2 = 0.f;
#pragma unroll
  for (int r = 0; r < 8; r++) {
    int row = row0 + r;
    if (row < rows) {
      float v = acc[r] + bb;
      Y[row * COLS + t] = v;
      a1 += v;
      a2 = fmaf(v, v, a2);
    }
  }
  atomicAdd(&ssum[t], a1);
  atomicAdd(&ssq[t], a2);
}

// ---------------- head ----------------
__global__ __launch_bounds__(64) void head_kernel(const float* __restrict__ u,
                                                  const float* __restrict__ W,
                                                  const float* __restrict__ b,
                                                  float* __restrict__ out) {
  __shared__ float row[128];
  int g = blockIdx.x;
  int t = threadIdx.x;
  row[t] = u[g * 128 + t];
  row[t + 64] = u[g * 128 + 64 + t];
  __syncthreads();
  if (t < 12) {
    float acc = b[t];
    for (int k = 0; k < 128; k++) acc = fmaf(row[k], W[k * 12 + t], acc);
    out[g * 12 + t] = 1.f / (1.f + expf(-acc));
  }
}

// ---------------- launcher ----------------
extern "C" void kernel_launch(void* const* d_in, const int* in_sizes, int n_in, void* d_out,
                              int out_size, void* d_ws, size_t ws_size, hipStream_t stream) {
  (void)in_sizes; (void)n_in; (void)out_size; (void)ws_size;
  const float* x       = (const float*)d_in[0];
  const int*   ei      = (const int*)d_in[1];
  const float* ea      = (const float*)d_in[2];
  const int*   batch   = (const int*)d_in[3];
  const float* in_W    = (const float*)d_in[4];
  const float* in_b    = (const float*)d_in[5];
  const float* in_g    = (const float*)d_in[6];
  const float* in_beta = (const float*)d_in[7];
  const float* Wl      = (const float*)d_in[8];
  const float* Wr      = (const float*)d_in[9];
  const float* We      = (const float*)d_in[10];
  const float* att     = (const float*)d_in[11];
  const float* conv_b  = (const float*)d_in[12];
  const float* bn_g    = (const float*)d_in[13];
  const float* bn_b    = (const float*)d_in[14];
  const float* t1_W    = (const float*)d_in[15];
  const float* t1_b    = (const float*)d_in[16];
  const float* t1_g    = (const float*)d_in[17];
  const float* t1_beta = (const float*)d_in[18];
  const float* t2_W    = (const float*)d_in[19];
  const float* t2_b    = (const float*)d_in[20];
  const float* t2_g    = (const float*)d_in[21];
  const float* t2_beta = (const float*)d_in[22];
  const float* head_W  = (const float*)d_in[23];
  const float* head_b  = (const float*)d_in[24];
  float* out = (float*)d_out;

  float* p = (float*)d_ws;
  float* xn   = p; p += N_ * H_;
  float* buf  = p; p += N_ * H_;
  float* ssum = p; p += 256;
  float* ssq  = p; p += 256;   // contiguous after ssum (joint memset)
  float* mean = p; p += 256;
  float* rstd = p; p += 256;
  float* xg   = p; p += G_ * 384;
  float* u1   = p; p += G_ * 256;
  float* u2   = p; p += G_ * 128;
  unsigned* up = (unsigned*)p;
  unsigned* xlb  = up; up += (size_t)N_ * 64;
  unsigned* xrb  = up; up += (size_t)N_ * 64;
  unsigned* easb = up; up += (size_t)E_ * 4 + 16;  // +4 uint4 pad for masked tail loads
  int* ip = (int*)up;
  int* deg    = ip; ip += N_;
  int* dcnt   = ip; ip += 64;   // contiguous after deg: joint memset
  int* eoff   = ip; ip += N_ + 1;
  int* cursor = ip; ip += N_;
  int* goff   = ip; ip += G_ + 1;
  int* esrc   = ip; ip += E_;
  int* bsum   = ip; ip += 64;
  int* boff   = ip; ip += 64;
  int* dcur   = ip; ip += 64;
  int* order  = ip; ip += N_;

  // ---- build CSR structures + degree-sorted node order ----
  hipMemsetAsync(deg, 0, (size_t)(N_ + 64) * sizeof(int), stream);
  hist_kernel<<<1024, 256, 0, stream>>>(ei + E_, E_, deg);
  scan_local<<<49, 1024, 0, stream>>>(deg, eoff, bsum, N_);
  scan_bsum<<<1, 64, 0, stream>>>(bsum, boff, 49);
  scan_add<<<49, 1024, 0, stream>>>(eoff, boff, cursor, N_);
  deg_hist<<<(N_ + 255) / 256, 256, 0, stream>>>(deg, dcnt);
  deg_scan<<<1, 64, 0, stream>>>(dcnt, dcur);
  deg_scatter<<<(N_ + 255) / 256, 256, 0, stream>>>(deg, dcur, order);
  edge_scatter<<<(E_ + 255) / 256, 256, 0, stream>>>(ei, ea, cursor, esrc, easb);
  goff_from_sorted<<<(N_ + 255) / 256, 256, 0, stream>>>(batch, goff);

  // ---- input layer ----
  hipMemsetAsync(ssum, 0, 512 * sizeof(float), stream);
  in_gemm<<<(N_ + 31) / 32, 256, 0, stream>>>(x, in_W, in_b, buf, ssum, ssq);
  bn_final<<<1, 256, 0, stream>>>(ssum, ssq, 1.f / N_, H_, mean, rstd);

  // ---- 3 GATv2 layers ----
  for (int l = 0; l < 3; l++) {
    if (l == 0) {
      gemm_xlxr<1><<<(N_ + 63) / 64, 256, 0, stream>>>(xn, xn, buf, in_g, in_beta, mean, rstd,
                                                       Wl + l * H_ * H_, Wr + l * H_ * H_,
                                                       xlb, xrb);
    } else {
      gemm_xlxr<2><<<(N_ + 63) / 64, 256, 0, stream>>>(xn, xn, buf, bn_g + (l - 1) * H_,
                                                       bn_b + (l - 1) * H_, mean, rstd,
                                                       Wl + l * H_ * H_, Wr + l * H_ * H_,
                                                       xlb, xrb);
    }
    agg_csr<<<2048, 256, 0, stream>>>(order, eoff, esrc, easb, We + l * 8 * H_, att + l * H_,
                                      xlb, xrb, conv_b + l * H_, buf, ssum, ssq);
    bn_final<<<1, 256, 0, stream>>>(ssum, ssq, 1.f / N_, H_, mean, rstd);
  }

  // ---- pooling with fused layer-2 residual ----
  pool_residual<<<G_, 128, 0, stream>>>(goff, xn, buf, bn_g + 2 * H_, bn_b + 2 * H_,
                                        mean, rstd, xg);

  // ---- t1 ----
  mlp_gemm<384, 256><<<G_ / 8, 256, 0, stream>>>(xg, t1_W, t1_b, u1, G_, ssum, ssq);
  bn_final<<<1, 256, 0, stream>>>(ssum, ssq, 1.f / G_, 256, mean, rstd);
  apply_bn_relu<<<(G_ * 256 + 255) / 256, 256, 0, stream>>>(u1, u1, t1_g, t1_beta, mean, rstd,
                                                            (long)G_ * 256, 255);

  // ---- t2 ----
  mlp_gemm<256, 128><<<G_ / 8, 128, 0, stream>>>(u1, t2_W, t2_b, u2, G_, ssum, ssq);
  bn_final<<<1, 256, 0, stream>>>(ssum, ssq, 1.f / G_, 128, mean, rstd);
  apply_bn_relu<<<(G_ * 128 + 255) / 256, 256, 0, stream>>>(u2, u2, t2_g, t2_beta, mean, rstd,
                                                            (long)G_ * 128, 127);

  // ---- head ----
  head_kernel<<<G_, 64, 0, stream>>>(u2, head_W, head_b, out);
}

// Round 8
// 915.336 us; speedup vs baseline: 1.6943x; 1.3548x over previous
//
#include <hip/hip_runtime.h>
#include <math.h>

// ToxicityGATv2 — round 8: degree sort removed (atomic-contention disaster),
// agg_csr reverted to proven round-5 body, gemm_xlxr rewritten with bf16 MFMA
// (16x16x32), bn_final eliminated via 6 per-stage stat buffers + inline finalize.

constexpr int N_ = 50000;
constexpr int E_ = 400000;
constexpr int G_ = 2000;
constexpr int H_ = 128;
constexpr int IN_ = 39;

typedef __attribute__((ext_vector_type(8))) short bf16x8;
typedef __attribute__((ext_vector_type(4))) float f32x4;

// ---------------- bf16 pack/unpack (RNE) ----------------
__device__ __forceinline__ unsigned pk_bf16(float a, float b) {
  unsigned ua = __float_as_uint(a);
  unsigned ub = __float_as_uint(b);
  ua = (ua + 0x7fffu + ((ua >> 16) & 1u)) >> 16;
  ub = (ub + 0x7fffu + ((ub >> 16) & 1u)) & 0xffff0000u;
  return ua | ub;
}
__device__ __forceinline__ unsigned short bf16_1(float x) {
  unsigned u = __float_as_uint(x);
  u = (u + 0x7fffu + ((u >> 16) & 1u)) >> 16;
  return (unsigned short)u;
}
__device__ __forceinline__ float up_lo(unsigned u) { return __uint_as_float(u << 16); }
__device__ __forceinline__ float up_hi(unsigned u) { return __uint_as_float(u & 0xffff0000u); }

// ---------------- histogram ----------------
__global__ __launch_bounds__(256) void hist_kernel(const int* __restrict__ keys, int n,
                                                   int* __restrict__ cnt) {
  for (int i = blockIdx.x * 256 + threadIdx.x; i < n; i += gridDim.x * 256)
    atomicAdd(&cnt[keys[i]], 1);
}

// ---------------- multi-block scan ----------------
__global__ __launch_bounds__(1024) void scan_local(const int* __restrict__ in,
                                                   int* __restrict__ outx,
                                                   int* __restrict__ bsum, int n) {
  __shared__ int wsum[16];
  int t = threadIdx.x, lane = t & 63, wid = t >> 6;
  int idx = blockIdx.x * 1024 + t;
  int v = (idx < n) ? in[idx] : 0;
  int x = v;
#pragma unroll
  for (int off = 1; off < 64; off <<= 1) {
    int y = __shfl_up(x, off, 64);
    if (lane >= off) x += y;
  }
  if (lane == 63) wsum[wid] = x;
  __syncthreads();
  if (t == 0) {
    int acc = 0;
#pragma unroll
    for (int w = 0; w < 16; w++) { int tmp = wsum[w]; wsum[w] = acc; acc += tmp; }
    bsum[blockIdx.x] = acc;
  }
  __syncthreads();
  if (idx < n) outx[idx] = wsum[wid] + x - v;
}

__global__ __launch_bounds__(64) void scan_bsum(const int* __restrict__ bsum,
                                                int* __restrict__ boff, int nb) {
  int t = threadIdx.x;
  int v = (t < nb) ? bsum[t] : 0;
  int x = v;
#pragma unroll
  for (int off = 1; off < 64; off <<= 1) {
    int y = __shfl_up(x, off, 64);
    if (t >= off) x += y;
  }
  boff[t] = x - v;
}

__global__ __launch_bounds__(1024) void scan_add(int* __restrict__ eoff,
                                                 const int* __restrict__ boff,
                                                 int* __restrict__ cursor, int n) {
  int idx = blockIdx.x * 1024 + threadIdx.x;
  if (idx < n) {
    int e = eoff[idx] + boff[idx >> 10];
    eoff[idx] = e;
    cursor[idx] = e;
  }
  if (idx == 0) eoff[n] = E_;
}

// ---------------- goff from sorted batch ----------------
__global__ __launch_bounds__(256) void goff_from_sorted(const int* __restrict__ batch,
                                                        int* __restrict__ goff) {
  int i = blockIdx.x * 256 + threadIdx.x;
  if (i >= N_) return;
  int bi = batch[i];
  int bp = (i == 0) ? -1 : batch[i - 1];
  for (int g = bp + 1; g <= bi; g++) goff[g] = i;
  if (i == N_ - 1) {
    for (int g = bi + 1; g <= G_; g++) goff[g] = N_;
  }
}

// ---------------- edge scatter (bf16 attrs) ----------------
__global__ __launch_bounds__(256) void edge_scatter(const int* __restrict__ ei,
                                                    const float* __restrict__ ea,
                                                    int* __restrict__ cursor,
                                                    int* __restrict__ esrc,
                                                    unsigned* __restrict__ easb) {
  int e = blockIdx.x * 256 + threadIdx.x;
  if (e >= E_) return;
  int src = ei[e];
  int dst = ei[E_ + e];
  int j = atomicAdd(&cursor[dst], 1);
  esrc[j] = src;
  const float4* eav = (const float4*)(ea + (size_t)e * 8);
  float4 a0 = eav[0], a1 = eav[1];
  uint4 o;
  o.x = pk_bf16(a0.x, a0.y);
  o.y = pk_bf16(a0.z, a0.w);
  o.z = pk_bf16(a1.x, a1.y);
  o.w = pk_bf16(a1.z, a1.w);
  ((uint4*)easb)[j] = o;
}

// ---------------- input GEMM + fused colstats ----------------
__global__ __launch_bounds__(256) void in_gemm(const float* __restrict__ x,
                                               const float* __restrict__ W,
                                               const float* __restrict__ b,
                                               float* __restrict__ y,
                                               float* __restrict__ ssum,
                                               float* __restrict__ ssq) {
  __shared__ float xs[32][40];
  __shared__ float s1[256], s2[256];
  int t = threadIdx.x;
  int row0 = blockIdx.x * 32;
  for (int i = t; i < 32 * IN_; i += 256) {
    int r = i / IN_, k = i % IN_;
    int row = row0 + r;
    xs[r][k] = (row < N_) ? x[row * IN_ + k] : 0.f;
  }
  __syncthreads();
  int col = t & 127;
  int half = t >> 7;
  float acc[16];
#pragma unroll
  for (int r = 0; r < 16; r++) acc[r] = 0.f;
  for (int k = 0; k < IN_; k++) {
    float w = W[k * H_ + col];
#pragma unroll
    for (int r = 0; r < 16; r++) acc[r] = fmaf(xs[half * 16 + r][k], w, acc[r]);
  }
  float bb = b[col];
  float a1 = 0.f, a2 = 0.f;
#pragma unroll
  for (int r = 0; r < 16; r++) {
    int row = row0 + half * 16 + r;
    float v = acc[r] + bb;
    if (row < N_) {
      y[row * H_ + col] = v;
      a1 += v;
      a2 = fmaf(v, v, a2);
    }
  }
  s1[t] = a1; s2[t] = a2;
  __syncthreads();
  if (t < 128) {
    atomicAdd(&ssum[t], s1[t] + s1[t + 128]);
    atomicAdd(&ssq[t], s2[t] + s2[t + 128]);
  }
}

// ---------------- MFMA node GEMM: xl|xr = bn_epilogue(xn) @ [Wl|Wr] ----------
// MODE 1: v=relu(bn(buf)); xn=v.  MODE 2: v=xn+elu(bn(buf)); xn=v.
// BN mean/rstd computed inline from ssum/ssq (no bn_final kernel).
// A staged bf16 in LDS (64x128), B staged per-32k chunk n-major (256x32).
template <int MODE>
__global__ __launch_bounds__(256) void gemm_mfma(float* __restrict__ xn,
                                                 const float* __restrict__ buf,
                                                 const float* __restrict__ g,
                                                 const float* __restrict__ beta,
                                                 const float* __restrict__ ssum,
                                                 const float* __restrict__ ssq,
                                                 float rows_inv,
                                                 const float* __restrict__ Wlp,
                                                 const float* __restrict__ Wrp,
                                                 unsigned* __restrict__ xlb,
                                                 unsigned* __restrict__ xrb) {
  __shared__ char smem[17408 + 20480];
  short (*a_s)[136] = (short(*)[136])smem;              // 64 rows x 128 k (pad 136)
  short (*b_s)[40] = (short(*)[40])(smem + 17408);      // 256 n x 32 k (pad 40)
  float* t2base = (float*)(smem + 17408);               // epilogue reuse
  int t = threadIdx.x;
  int lane = t & 63, w = t >> 6;
  int quad = lane >> 4, lc = lane & 15;
  int row0 = blockIdx.x * 64;

  // ---- stage A (fused BN epilogue, fp32 xn updated, bf16 into LDS) ----
  {
    int r = t >> 2;
    int row = row0 + r;
    int kb0 = (t & 3) * 32;
    bool valid = row < N_;
    for (int kk = 0; kk < 32; kk += 4) {
      int c = kb0 + kk;
      float4 v = make_float4(0.f, 0.f, 0.f, 0.f);
      if (valid) {
        float4 bv = *(const float4*)&buf[(size_t)row * H_ + c];
        float4 gv = *(const float4*)&g[c];
        float4 be = *(const float4*)&beta[c];
        float4 s1 = *(const float4*)&ssum[c];
        float4 s2 = *(const float4*)&ssq[c];
        float m0 = s1.x * rows_inv, m1 = s1.y * rows_inv, m2 = s1.z * rows_inv, m3 = s1.w * rows_inv;
        float r0 = rsqrtf(s2.x * rows_inv - m0 * m0 + 1e-5f);
        float r1 = rsqrtf(s2.y * rows_inv - m1 * m1 + 1e-5f);
        float r2 = rsqrtf(s2.z * rows_inv - m2 * m2 + 1e-5f);
        float r3 = rsqrtf(s2.w * rows_inv - m3 * m3 + 1e-5f);
        float t0 = gv.x * (bv.x - m0) * r0 + be.x;
        float t1 = gv.y * (bv.y - m1) * r1 + be.y;
        float t2 = gv.z * (bv.z - m2) * r2 + be.z;
        float t3 = gv.w * (bv.w - m3) * r3 + be.w;
        if (MODE == 1) {
          v = make_float4(fmaxf(t0, 0.f), fmaxf(t1, 0.f), fmaxf(t2, 0.f), fmaxf(t3, 0.f));
        } else {
          float4 xo = *(const float4*)&xn[(size_t)row * H_ + c];
          v.x = xo.x + ((t0 > 0.f) ? t0 : (__expf(t0) - 1.f));
          v.y = xo.y + ((t1 > 0.f) ? t1 : (__expf(t1) - 1.f));
          v.z = xo.z + ((t2 > 0.f) ? t2 : (__expf(t2) - 1.f));
          v.w = xo.w + ((t3 > 0.f) ? t3 : (__expf(t3) - 1.f));
        }
        *(float4*)&xn[(size_t)row * H_ + c] = v;
      }
      uint2 pk;
      pk.x = pk_bf16(v.x, v.y);
      pk.y = pk_bf16(v.z, v.w);
      *(uint2*)&a_s[r][c] = pk;
    }
  }

  f32x4 acc[16];
#pragma unroll
  for (int nt = 0; nt < 16; nt++) acc[nt] = (f32x4){0.f, 0.f, 0.f, 0.f};

  for (int kb = 0; kb < 4; kb++) {
    __syncthreads();
    // stage B chunk: b_s[n][k_local] = bf16(W[kb*32+k_local][n]), n 0..255
    for (int i = t; i < 2048; i += 256) {
      int k_local = i >> 6;
      int n4 = (i & 63) << 2;
      const float* Wsrc = (n4 < 128) ? Wlp : Wrp;
      int nn = (n4 < 128) ? n4 : n4 - 128;
      float4 wv = *(const float4*)&Wsrc[(kb * 32 + k_local) * H_ + nn];
      b_s[n4 + 0][k_local] = bf16_1(wv.x);
      b_s[n4 + 1][k_local] = bf16_1(wv.y);
      b_s[n4 + 2][k_local] = bf16_1(wv.z);
      b_s[n4 + 3][k_local] = bf16_1(wv.w);
    }
    __syncthreads();
    bf16x8 av = *(const bf16x8*)&a_s[w * 16 + lc][kb * 32 + quad * 8];
#pragma unroll
    for (int nt = 0; nt < 16; nt++) {
      bf16x8 bv = *(const bf16x8*)&b_s[nt * 16 + lc][quad * 8];
      acc[nt] = __builtin_amdgcn_mfma_f32_16x16x32_bf16(av, bv, acc[nt], 0, 0, 0);
    }
  }
  __syncthreads();  // b_s -> t2 reuse

  // ---- epilogue: transpose 16x32 chunks via LDS, packed coalesced stores ----
  float* t2 = t2base + w * 544;  // 16 rows x 34 cols fp32, per-wave private
  for (int ntp = 0; ntp < 8; ntp++) {
#pragma unroll
    for (int rr = 0; rr < 4; rr++) {
      t2[(quad * 4 + rr) * 34 + lc] = acc[2 * ntp][rr];
      t2[(quad * 4 + rr) * 34 + 16 + lc] = acc[2 * ntp + 1][rr];
    }
    __asm__ volatile("s_waitcnt lgkmcnt(0)" ::: "memory");
#pragma unroll
    for (int it = 0; it < 4; it++) {
      int item = lane + it * 64;
      int p = item & 15, rowi = item >> 4;
      float v0 = t2[rowi * 34 + 2 * p];
      float v1 = t2[rowi * 34 + 2 * p + 1];
      unsigned u = pk_bf16(v0, v1);
      int colpair = ntp * 16 + p;
      int rowg = row0 + w * 16 + rowi;
      if (rowg < N_) {
        if (colpair < 64) xlb[(size_t)rowg * 64 + colpair] = u;
        else xrb[(size_t)rowg * 64 + colpair - 64] = u;
      }
    }
    __asm__ volatile("s_waitcnt lgkmcnt(0)" ::: "memory");
  }
}

// ---------------- CSR aggregation (round-5 proven body) ----------------
__device__ __forceinline__ float ep8u(const uint4& u, const float* w) {
  float ep = up_lo(u.x) * w[0];
  ep = fmaf(up_hi(u.x), w[1], ep);
  ep = fmaf(up_lo(u.y), w[2], ep);
  ep = fmaf(up_hi(u.y), w[3], ep);
  ep = fmaf(up_lo(u.z), w[4], ep);
  ep = fmaf(up_hi(u.z), w[5], ep);
  ep = fmaf(up_lo(u.w), w[6], ep);
  ep = fmaf(up_hi(u.w), w[7], ep);
  return ep;
}

__global__ __launch_bounds__(256) void agg_csr(const int* __restrict__ eoff,
                                               const int* __restrict__ esrc,
                                               const unsigned* __restrict__ easb,
                                               const float* __restrict__ Wel,
                                               const float* __restrict__ attl,
                                               const unsigned* __restrict__ xlb,
                                               const unsigned* __restrict__ xrb,
                                               const float* __restrict__ cb,
                                               float* __restrict__ buf,
                                               float* __restrict__ ssum,
                                               float* __restrict__ ssq) {
  __shared__ float sA[256], sB[256], sC[256], sD[256];
  int t = threadIdx.x;
  int l = t & 63;
  int sub = t >> 6;
  int c0 = l * 2;
  float w0[8], w1[8];
#pragma unroll
  for (int k = 0; k < 8; k++) {
    float2 wv = *(const float2*)&Wel[k * H_ + c0];
    w0[k] = wv.x; w1[k] = wv.y;
  }
  float2 attv = *(const float2*)&attl[c0];
  float2 cbv = *(const float2*)&cb[c0];
  const uint4* eas4 = (const uint4*)easb;
  float a1_0 = 0.f, a1_1 = 0.f, a2_0 = 0.f, a2_1 = 0.f;
  for (int n = blockIdx.x * 4 + sub; n < N_; n += gridDim.x * 4) {
    unsigned xru = xrb[(size_t)n * 64 + l];
    float xr0 = up_lo(xru), xr1 = up_hi(xru);
    int e0 = eoff[n], e1 = eoff[n + 1];
    float acc0 = 0.f, acc1 = 0.f, den = 0.f;
    int j = e0;
    for (; j + 4 <= e1; j += 4) {
      int s0 = esrc[j], s1 = esrc[j + 1], s2 = esrc[j + 2], s3 = esrc[j + 3];
      uint4 u0 = eas4[j], u1 = eas4[j + 1], u2 = eas4[j + 2], u3 = eas4[j + 3];
      unsigned xu0 = xlb[(size_t)s0 * 64 + l];
      unsigned xu1 = xlb[(size_t)s1 * 64 + l];
      unsigned xu2 = xlb[(size_t)s2 * 64 + l];
      unsigned xu3 = xlb[(size_t)s3 * 64 + l];
      float x00 = up_lo(xu0), x01 = up_hi(xu0);
      float x10 = up_lo(xu1), x11 = up_hi(xu1);
      float x20 = up_lo(xu2), x21 = up_hi(xu2);
      float x30 = up_lo(xu3), x31 = up_hi(xu3);
      float m00 = x00 + xr0 + ep8u(u0, w0);
      float m01 = x01 + xr1 + ep8u(u0, w1);
      float m10 = x10 + xr0 + ep8u(u1, w0);
      float m11 = x11 + xr1 + ep8u(u1, w1);
      float m20 = x20 + xr0 + ep8u(u2, w0);
      float m21 = x21 + xr1 + ep8u(u2, w1);
      float m30 = x30 + xr0 + ep8u(u3, w0);
      float m31 = x31 + xr1 + ep8u(u3, w1);
      m00 = (m00 > 0.f) ? m00 : 0.2f * m00;
      m01 = (m01 > 0.f) ? m01 : 0.2f * m01;
      m10 = (m10 > 0.f) ? m10 : 0.2f * m10;
      m11 = (m11 > 0.f) ? m11 : 0.2f * m11;
      m20 = (m20 > 0.f) ? m20 : 0.2f * m20;
      m21 = (m21 > 0.f) ? m21 : 0.2f * m21;
      m30 = (m30 > 0.f) ? m30 : 0.2f * m30;
      m31 = (m31 > 0.f) ? m31 : 0.2f * m31;
      float p0 = fmaf(m00, attv.x, m01 * attv.y);
      float p1 = fmaf(m10, attv.x, m11 * attv.y);
      float p2 = fmaf(m20, attv.x, m21 * attv.y);
      float p3 = fmaf(m30, attv.x, m31 * attv.y);
#pragma unroll
      for (int off = 8; off > 0; off >>= 1) {
        p0 += __shfl_xor(p0, off, 64);
        p1 += __shfl_xor(p1, off, 64);
        p2 += __shfl_xor(p2, off, 64);
        p3 += __shfl_xor(p3, off, 64);
      }
      float e0v = __expf(p0), e1v = __expf(p1), e2v = __expf(p2), e3v = __expf(p3);
      acc0 = fmaf(e0v, x00, acc0); acc1 = fmaf(e0v, x01, acc1);
      acc0 = fmaf(e1v, x10, acc0); acc1 = fmaf(e1v, x11, acc1);
      acc0 = fmaf(e2v, x20, acc0); acc1 = fmaf(e2v, x21, acc1);
      acc0 = fmaf(e3v, x30, acc0); acc1 = fmaf(e3v, x31, acc1);
      den += (e0v + e1v) + (e2v + e3v);
    }
    for (; j < e1; j++) {
      int s0 = esrc[j];
      uint4 u0 = eas4[j];
      unsigned xu0 = xlb[(size_t)s0 * 64 + l];
      float x00 = up_lo(xu0), x01 = up_hi(xu0);
      float m00 = x00 + xr0 + ep8u(u0, w0);
      float m01 = x01 + xr1 + ep8u(u0, w1);
      m00 = (m00 > 0.f) ? m00 : 0.2f * m00;
      m01 = (m01 > 0.f) ? m01 : 0.2f * m01;
      float p0 = fmaf(m00, attv.x, m01 * attv.y);
#pragma unroll
      for (int off = 8; off > 0; off >>= 1) p0 += __shfl_xor(p0, off, 64);
      float e0v = __expf(p0);
      acc0 = fmaf(e0v, x00, acc0);
      acc1 = fmaf(e0v, x01, acc1);
      den += e0v;
    }
    float inv = 1.f / (den + 1e-16f);
    float h0 = acc0 * inv + cbv.x;
    float h1 = acc1 * inv + cbv.y;
    *(float2*)&buf[(size_t)n * H_ + c0] = make_float2(h0, h1);
    a1_0 += h0; a1_1 += h1;
    a2_0 = fmaf(h0, h0, a2_0); a2_1 = fmaf(h1, h1, a2_1);
  }
  sA[t] = a1_0; sB[t] = a1_1; sC[t] = a2_0; sD[t] = a2_1;
  __syncthreads();
  if (t < 64) {
    float r1 = sA[t] + sA[t + 64] + sA[t + 128] + sA[t + 192];
    float r2 = sB[t] + sB[t + 64] + sB[t + 128] + sB[t + 192];
    float r3 = sC[t] + sC[t + 64] + sC[t + 128] + sC[t + 192];
    float r4 = sD[t] + sD[t + 64] + sD[t + 128] + sD[t + 192];
    atomicAdd(&ssum[2 * t], r1);
    atomicAdd(&ssum[2 * t + 1], r2);
    atomicAdd(&ssq[2 * t], r3);
    atomicAdd(&ssq[2 * t + 1], r4);
  }
}

// ---------------- BN apply with inline finalize ----------------
__global__ __launch_bounds__(256) void apply_bn_relu(const float* __restrict__ y,
                                                     float* __restrict__ out,
                                                     const float* __restrict__ g,
                                                     const float* __restrict__ beta,
                                                     const float* __restrict__ ssum,
                                                     const float* __restrict__ ssq,
                                                     float rows_inv,
                                                     long total, int cmask) {
  long i = (long)blockIdx.x * 256 + threadIdx.x;
  if (i >= total) return;
  int c = (int)i & cmask;
  float m = ssum[c] * rows_inv;
  float rs = rsqrtf(ssq[c] * rows_inv - m * m + 1e-5f);
  float v = g[c] * (y[i] - m) * rs + beta[c];
  out[i] = fmaxf(v, 0.f);
}

// ---------------- pooling with fused layer-2 residual (inline BN finalize) ----
__global__ __launch_bounds__(128) void pool_residual(const int* __restrict__ goff,
                                                     const float* __restrict__ xn,
                                                     const float* __restrict__ buf,
                                                     const float* __restrict__ g,
                                                     const float* __restrict__ beta,
                                                     const float* __restrict__ ssum,
                                                     const float* __restrict__ ssq,
                                                     float rows_inv,
                                                     float* __restrict__ xg) {
  int gr = blockIdx.x;
  int t = threadIdx.x;
  int n0 = goff[gr], n1 = goff[gr + 1];
  float mm = ssum[t] * rows_inv;
  float rr = rsqrtf(ssq[t] * rows_inv - mm * mm + 1e-5f);
  float gg = g[t], bb = beta[t];
  float s = 0.f, mx = -INFINITY;
  for (int n = n0; n < n1; n++) {
    float w = gg * (buf[(size_t)n * H_ + t] - mm) * rr + bb;
    w = (w > 0.f) ? w : (__expf(w) - 1.f);
    float v = xn[(size_t)n * H_ + t] + w;
    s += v;
    mx = fmaxf(mx, v);
  }
  float c = (float)(n1 - n0);
  xg[gr * 384 + t] = s / fmaxf(c, 1.f);
  xg[gr * 384 + 128 + t] = (c > 0.f) ? mx : 0.f;
  xg[gr * 384 + 256 + t] = s;
}

// ---------------- MLP GEMMs (fused colstats) ----------------
template <int K, int COLS>
__global__ void mlp_gemm(const float* __restrict__ A, const float* __restrict__ W,
                         const float* __restrict__ b, float* __restrict__ Y, int rows,
                         float* __restrict__ ssum, float* __restrict__ ssq) {
  __shared__ float xs[8][K];
  int t = threadIdx.x;
  int row0 = blockIdx.x * 8;
  for (int i = t; i < 8 * K; i += COLS) {
    int r = i / K, k = i % K;
    int row = row0 + r;
    xs[r][k] = (row < rows) ? A[row * K + k] : 0.f;
  }
  __syncthreads();
  float acc[8];
#pragma unroll
  for (int r = 0; r < 8; r++) acc[r] = 0.f;
  for (int k = 0; k < K; k++) {
    float w = W[k * COLS + t];
#pragma unroll
    for (int r = 0; r < 8; r++) acc[r] = fmaf(xs[r][k], w, acc[r]);
  }
  float bb = b[t];
  float a1 = 0.f, a2 = 0.f;
#pragma unroll
  for (int r = 0; r < 8; r++) {
    int row = row0 + r;
    if (row < rows) {
      float v = acc[r] + bb;
      Y[row * COLS + t] = v;
      a1 += v;
      a2 = fmaf(v, v, a2);
    }
  }
  atomicAdd(&ssum[t], a1);
  atomicAdd(&ssq[t], a2);
}

// ---------------- head ----------------
__global__ __launch_bounds__(64) void head_kernel(const float* __restrict__ u,
                                                  const float* __restrict__ W,
                                                  const float* __restrict__ b,
                                                  float* __restrict__ out) {
  __shared__ float row[128];
  int g = blockIdx.x;
  int t = threadIdx.x;
  row[t] = u[g * 128 + t];
  row[t + 64] = u[g * 128 + 64 + t];
  __syncthreads();
  if (t < 12) {
    float acc = b[t];
    for (int k = 0; k < 128; k++) acc = fmaf(row[k], W[k * 12 + t], acc);
    out[g * 12 + t] = 1.f / (1.f + expf(-acc));
  }
}

// ---------------- launcher ----------------
extern "C" void kernel_launch(void* const* d_in, const int* in_sizes, int n_in, void* d_out,
                              int out_size, void* d_ws, size_t ws_size, hipStream_t stream) {
  (void)in_sizes; (void)n_in; (void)out_size; (void)ws_size;
  const float* x       = (const float*)d_in[0];
  const int*   ei      = (const int*)d_in[1];
  const float* ea      = (const float*)d_in[2];
  const int*   batch   = (const int*)d_in[3];
  const float* in_W    = (const float*)d_in[4];
  const float* in_b    = (const float*)d_in[5];
  const float* in_g    = (const float*)d_in[6];
  const float* in_beta = (const float*)d_in[7];
  const float* Wl      = (const float*)d_in[8];
  const float* Wr      = (const float*)d_in[9];
  const float* We      = (const float*)d_in[10];
  const float* att     = (const float*)d_in[11];
  const float* conv_b  = (const float*)d_in[12];
  const float* bn_g    = (const float*)d_in[13];
  const float* bn_b    = (const float*)d_in[14];
  const float* t1_W    = (const float*)d_in[15];
  const float* t1_b    = (const float*)d_in[16];
  const float* t1_g    = (const float*)d_in[17];
  const float* t1_beta = (const float*)d_in[18];
  const float* t2_W    = (const float*)d_in[19];
  const float* t2_b    = (const float*)d_in[20];
  const float* t2_g    = (const float*)d_in[21];
  const float* t2_beta = (const float*)d_in[22];
  const float* head_W  = (const float*)d_in[23];
  const float* head_b  = (const float*)d_in[24];
  float* out = (float*)d_out;

  float* p = (float*)d_ws;
  float* xn    = p; p += N_ * H_;
  float* buf   = p; p += N_ * H_;
  float* sstat = p; p += 6 * 512;   // 6 stages x (ssum 256 | ssq 256)
  float* xg    = p; p += G_ * 384;
  float* u1    = p; p += G_ * 256;
  float* u2    = p; p += G_ * 128;
  unsigned* up = (unsigned*)p;
  unsigned* xlb  = up; up += (size_t)N_ * 64;
  unsigned* xrb  = up; up += (size_t)N_ * 64;
  unsigned* easb = up; up += (size_t)E_ * 4;
  int* ip = (int*)up;
  int* deg    = ip; ip += N_;
  int* eoff   = ip; ip += N_ + 1;
  int* cursor = ip; ip += N_;
  int* goff   = ip; ip += G_ + 1;
  int* esrc   = ip; ip += E_;
  int* bsum   = ip; ip += 64;
  int* boff   = ip; ip += 64;

#define SSUM(s) (sstat + (s) * 512)
#define SSQ(s)  (sstat + (s) * 512 + 256)

  // ---- build CSR structures ----
  hipMemsetAsync(deg, 0, (size_t)N_ * sizeof(int), stream);
  hipMemsetAsync(sstat, 0, 6 * 512 * sizeof(float), stream);
  hist_kernel<<<1024, 256, 0, stream>>>(ei + E_, E_, deg);
  scan_local<<<49, 1024, 0, stream>>>(deg, eoff, bsum, N_);
  scan_bsum<<<1, 64, 0, stream>>>(bsum, boff, 49);
  scan_add<<<49, 1024, 0, stream>>>(eoff, boff, cursor, N_);
  edge_scatter<<<(E_ + 255) / 256, 256, 0, stream>>>(ei, ea, cursor, esrc, easb);
  goff_from_sorted<<<(N_ + 255) / 256, 256, 0, stream>>>(batch, goff);

  // ---- input layer (stats -> stage 0) ----
  in_gemm<<<(N_ + 31) / 32, 256, 0, stream>>>(x, in_W, in_b, buf, SSUM(0), SSQ(0));

  // ---- 3 GATv2 layers (conv stats of layer l -> stage l+1) ----
  const float rnInv = 1.f / N_;
  for (int l = 0; l < 3; l++) {
    if (l == 0) {
      gemm_mfma<1><<<782, 256, 0, stream>>>(xn, buf, in_g, in_beta, SSUM(0), SSQ(0), rnInv,
                                            Wl + l * H_ * H_, Wr + l * H_ * H_, xlb, xrb);
    } else {
      gemm_mfma<2><<<782, 256, 0, stream>>>(xn, buf, bn_g + (l - 1) * H_, bn_b + (l - 1) * H_,
                                            SSUM(l), SSQ(l), rnInv,
                                            Wl + l * H_ * H_, Wr + l * H_ * H_, xlb, xrb);
    }
    agg_csr<<<2048, 256, 0, stream>>>(eoff, esrc, easb, We + l * 8 * H_, att + l * H_,
                                      xlb, xrb, conv_b + l * H_, buf, SSUM(l + 1), SSQ(l + 1));
  }

  // ---- pooling with fused layer-2 residual (stage 3 stats) ----
  pool_residual<<<G_, 128, 0, stream>>>(goff, xn, buf, bn_g + 2 * H_, bn_b + 2 * H_,
                                        SSUM(3), SSQ(3), rnInv, xg);

  // ---- t1 (stats -> stage 4) ----
  const float rgInv = 1.f / G_;
  mlp_gemm<384, 256><<<G_ / 8, 256, 0, stream>>>(xg, t1_W, t1_b, u1, G_, SSUM(4), SSQ(4));
  apply_bn_relu<<<(G_ * 256 + 255) / 256, 256, 0, stream>>>(u1, u1, t1_g, t1_beta,
                                                            SSUM(4), SSQ(4), rgInv,
                                                            (long)G_ * 256, 255);

  // ---- t2 (stats -> stage 5) ----
  mlp_gemm<256, 128><<<G_ / 8, 128, 0, stream>>>(u1, t2_W, t2_b, u2, G_, SSUM(5), SSQ(5));
  apply_bn_relu<<<(G_ * 128 + 255) / 256, 256, 0, stream>>>(u2, u2, t2_g, t2_beta,
                                                            SSUM(5), SSQ(5), rgInv,
                                                            (long)G_ * 128, 127);

  // ---- head ----
  head_kernel<<<G_, 64, 0, stream>>>(u2, head_W, head_b, out);
#undef SSUM
#undef SSQ
}

// Round 9
// 847.310 us; speedup vs baseline: 1.8303x; 1.0803x over previous
//
#include <hip/hip_runtime.h>
#include <math.h>

// ToxicityGATv2 — round 9: pre-packed bf16 weights (pack_weights prep kernel)
// so gemm_mfma's B-staging is pure vectorized LDS copies; round-8 structure
// otherwise unchanged (agg = round-5 proven body, per-stage stat buffers).

constexpr int N_ = 50000;
constexpr int E_ = 400000;
constexpr int G_ = 2000;
constexpr int H_ = 128;
constexpr int IN_ = 39;

typedef __attribute__((ext_vector_type(8))) short bf16x8;
typedef __attribute__((ext_vector_type(4))) float f32x4;

// ---------------- bf16 pack/unpack (RNE) ----------------
__device__ __forceinline__ unsigned pk_bf16(float a, float b) {
  unsigned ua = __float_as_uint(a);
  unsigned ub = __float_as_uint(b);
  ua = (ua + 0x7fffu + ((ua >> 16) & 1u)) >> 16;
  ub = (ub + 0x7fffu + ((ub >> 16) & 1u)) & 0xffff0000u;
  return ua | ub;
}
__device__ __forceinline__ unsigned short bf16_1(float x) {
  unsigned u = __float_as_uint(x);
  u = (u + 0x7fffu + ((u >> 16) & 1u)) >> 16;
  return (unsigned short)u;
}
__device__ __forceinline__ float up_lo(unsigned u) { return __uint_as_float(u << 16); }
__device__ __forceinline__ float up_hi(unsigned u) { return __uint_as_float(u & 0xffff0000u); }

// ---------------- histogram ----------------
__global__ __launch_bounds__(256) void hist_kernel(const int* __restrict__ keys, int n,
                                                   int* __restrict__ cnt) {
  for (int i = blockIdx.x * 256 + threadIdx.x; i < n; i += gridDim.x * 256)
    atomicAdd(&cnt[keys[i]], 1);
}

// ---------------- multi-block scan ----------------
__global__ __launch_bounds__(1024) void scan_local(const int* __restrict__ in,
                                                   int* __restrict__ outx,
                                                   int* __restrict__ bsum, int n) {
  __shared__ int wsum[16];
  int t = threadIdx.x, lane = t & 63, wid = t >> 6;
  int idx = blockIdx.x * 1024 + t;
  int v = (idx < n) ? in[idx] : 0;
  int x = v;
#pragma unroll
  for (int off = 1; off < 64; off <<= 1) {
    int y = __shfl_up(x, off, 64);
    if (lane >= off) x += y;
  }
  if (lane == 63) wsum[wid] = x;
  __syncthreads();
  if (t == 0) {
    int acc = 0;
#pragma unroll
    for (int w = 0; w < 16; w++) { int tmp = wsum[w]; wsum[w] = acc; acc += tmp; }
    bsum[blockIdx.x] = acc;
  }
  __syncthreads();
  if (idx < n) outx[idx] = wsum[wid] + x - v;
}

__global__ __launch_bounds__(64) void scan_bsum(const int* __restrict__ bsum,
                                                int* __restrict__ boff, int nb) {
  int t = threadIdx.x;
  int v = (t < nb) ? bsum[t] : 0;
  int x = v;
#pragma unroll
  for (int off = 1; off < 64; off <<= 1) {
    int y = __shfl_up(x, off, 64);
    if (t >= off) x += y;
  }
  boff[t] = x - v;
}

__global__ __launch_bounds__(1024) void scan_add(int* __restrict__ eoff,
                                                 const int* __restrict__ boff,
                                                 int* __restrict__ cursor, int n) {
  int idx = blockIdx.x * 1024 + threadIdx.x;
  if (idx < n) {
    int e = eoff[idx] + boff[idx >> 10];
    eoff[idx] = e;
    cursor[idx] = e;
  }
  if (idx == 0) eoff[n] = E_;
}

// ---------------- goff from sorted batch ----------------
__global__ __launch_bounds__(256) void goff_from_sorted(const int* __restrict__ batch,
                                                        int* __restrict__ goff) {
  int i = blockIdx.x * 256 + threadIdx.x;
  if (i >= N_) return;
  int bi = batch[i];
  int bp = (i == 0) ? -1 : batch[i - 1];
  for (int g = bp + 1; g <= bi; g++) goff[g] = i;
  if (i == N_ - 1) {
    for (int g = bi + 1; g <= G_; g++) goff[g] = N_;
  }
}

// ---------------- edge scatter (bf16 attrs) ----------------
__global__ __launch_bounds__(256) void edge_scatter(const int* __restrict__ ei,
                                                    const float* __restrict__ ea,
                                                    int* __restrict__ cursor,
                                                    int* __restrict__ esrc,
                                                    unsigned* __restrict__ easb) {
  int e = blockIdx.x * 256 + threadIdx.x;
  if (e >= E_) return;
  int src = ei[e];
  int dst = ei[E_ + e];
  int j = atomicAdd(&cursor[dst], 1);
  esrc[j] = src;
  const float4* eav = (const float4*)(ea + (size_t)e * 8);
  float4 a0 = eav[0], a1 = eav[1];
  uint4 o;
  o.x = pk_bf16(a0.x, a0.y);
  o.y = pk_bf16(a0.z, a0.w);
  o.z = pk_bf16(a1.x, a1.y);
  o.w = pk_bf16(a1.z, a1.w);
  ((uint4*)easb)[j] = o;
}

// ---------------- weight pre-pack: wpack[l][n][k] = bf16([Wl|Wr][k][n]) -------
__global__ __launch_bounds__(256) void pack_weights(const float* __restrict__ Wl,
                                                    const float* __restrict__ Wr,
                                                    unsigned short* __restrict__ wpack) {
  int i = blockIdx.x * 256 + threadIdx.x;  // enumerate (l, k, n) read-coalesced
  if (i >= 3 * 128 * 256) return;
  int l = i >> 15;
  int rem = i & 32767;
  int k = rem >> 8;
  int n = rem & 255;
  const float* Wsrc = (n < 128) ? (Wl + l * H_ * H_) : (Wr + l * H_ * H_);
  int nn = n & 127;
  wpack[(size_t)l * 32768 + n * 128 + k] = bf16_1(Wsrc[k * H_ + nn]);
}

// ---------------- input GEMM + fused colstats ----------------
__global__ __launch_bounds__(256) void in_gemm(const float* __restrict__ x,
                                               const float* __restrict__ W,
                                               const float* __restrict__ b,
                                               float* __restrict__ y,
                                               float* __restrict__ ssum,
                                               float* __restrict__ ssq) {
  __shared__ float xs[32][40];
  __shared__ float s1[256], s2[256];
  int t = threadIdx.x;
  int row0 = blockIdx.x * 32;
  for (int i = t; i < 32 * IN_; i += 256) {
    int r = i / IN_, k = i % IN_;
    int row = row0 + r;
    xs[r][k] = (row < N_) ? x[row * IN_ + k] : 0.f;
  }
  __syncthreads();
  int col = t & 127;
  int half = t >> 7;
  float acc[16];
#pragma unroll
  for (int r = 0; r < 16; r++) acc[r] = 0.f;
  for (int k = 0; k < IN_; k++) {
    float w = W[k * H_ + col];
#pragma unroll
    for (int r = 0; r < 16; r++) acc[r] = fmaf(xs[half * 16 + r][k], w, acc[r]);
  }
  float bb = b[col];
  float a1 = 0.f, a2 = 0.f;
#pragma unroll
  for (int r = 0; r < 16; r++) {
    int row = row0 + half * 16 + r;
    float v = acc[r] + bb;
    if (row < N_) {
      y[row * H_ + col] = v;
      a1 += v;
      a2 = fmaf(v, v, a2);
    }
  }
  s1[t] = a1; s2[t] = a2;
  __syncthreads();
  if (t < 128) {
    atomicAdd(&ssum[t], s1[t] + s1[t + 128]);
    atomicAdd(&ssq[t], s2[t] + s2[t + 128]);
  }
}

// ---------------- MFMA node GEMM (pre-packed bf16 B) ----------
// MODE 1: v=relu(bn(buf)); xn=v.  MODE 2: v=xn+elu(bn(buf)); xn=v.
template <int MODE>
__global__ __launch_bounds__(256) void gemm_mfma(float* __restrict__ xn,
                                                 const float* __restrict__ buf,
                                                 const float* __restrict__ g,
                                                 const float* __restrict__ beta,
                                                 const float* __restrict__ ssum,
                                                 const float* __restrict__ ssq,
                                                 float rows_inv,
                                                 const unsigned short* __restrict__ wp,
                                                 unsigned* __restrict__ xlb,
                                                 unsigned* __restrict__ xrb) {
  __shared__ char smem[17408 + 20480];
  short (*a_s)[136] = (short(*)[136])smem;              // 64 rows x 128 k (pad 136)
  short (*b_s)[40] = (short(*)[40])(smem + 17408);      // 256 n x 32 k (pad 40)
  float* t2base = (float*)(smem + 17408);               // epilogue reuse
  int t = threadIdx.x;
  int lane = t & 63, w = t >> 6;
  int quad = lane >> 4, lc = lane & 15;
  int row0 = blockIdx.x * 64;

  // ---- stage A (fused BN epilogue, fp32 xn updated, bf16 into LDS) ----
  {
    int r = t >> 2;
    int row = row0 + r;
    int kb0 = (t & 3) * 32;
    bool valid = row < N_;
    for (int kk = 0; kk < 32; kk += 4) {
      int c = kb0 + kk;
      float4 v = make_float4(0.f, 0.f, 0.f, 0.f);
      if (valid) {
        float4 bv = *(const float4*)&buf[(size_t)row * H_ + c];
        float4 gv = *(const float4*)&g[c];
        float4 be = *(const float4*)&beta[c];
        float4 s1 = *(const float4*)&ssum[c];
        float4 s2 = *(const float4*)&ssq[c];
        float m0 = s1.x * rows_inv, m1 = s1.y * rows_inv, m2 = s1.z * rows_inv, m3 = s1.w * rows_inv;
        float r0 = rsqrtf(s2.x * rows_inv - m0 * m0 + 1e-5f);
        float r1 = rsqrtf(s2.y * rows_inv - m1 * m1 + 1e-5f);
        float r2 = rsqrtf(s2.z * rows_inv - m2 * m2 + 1e-5f);
        float r3 = rsqrtf(s2.w * rows_inv - m3 * m3 + 1e-5f);
        float t0 = gv.x * (bv.x - m0) * r0 + be.x;
        float t1 = gv.y * (bv.y - m1) * r1 + be.y;
        float t2 = gv.z * (bv.z - m2) * r2 + be.z;
        float t3 = gv.w * (bv.w - m3) * r3 + be.w;
        if (MODE == 1) {
          v = make_float4(fmaxf(t0, 0.f), fmaxf(t1, 0.f), fmaxf(t2, 0.f), fmaxf(t3, 0.f));
        } else {
          float4 xo = *(const float4*)&xn[(size_t)row * H_ + c];
          v.x = xo.x + ((t0 > 0.f) ? t0 : (__expf(t0) - 1.f));
          v.y = xo.y + ((t1 > 0.f) ? t1 : (__expf(t1) - 1.f));
          v.z = xo.z + ((t2 > 0.f) ? t2 : (__expf(t2) - 1.f));
          v.w = xo.w + ((t3 > 0.f) ? t3 : (__expf(t3) - 1.f));
        }
        *(float4*)&xn[(size_t)row * H_ + c] = v;
      }
      uint2 pk;
      pk.x = pk_bf16(v.x, v.y);
      pk.y = pk_bf16(v.z, v.w);
      *(uint2*)&a_s[r][c] = pk;
    }
  }

  f32x4 acc[16];
#pragma unroll
  for (int nt = 0; nt < 16; nt++) acc[nt] = (f32x4){0.f, 0.f, 0.f, 0.f};

  for (int kb = 0; kb < 4; kb++) {
    __syncthreads();
    // stage B chunk: vectorized copy from pre-packed weights (16 KB)
    for (int i = t; i < 1024; i += 256) {
      int n = i >> 2;
      int k8 = (i & 3) * 8;
      *(uint4*)&b_s[n][k8] = *(const uint4*)&wp[(size_t)n * 128 + kb * 32 + k8];
    }
    __syncthreads();
    bf16x8 av = *(const bf16x8*)&a_s[w * 16 + lc][kb * 32 + quad * 8];
#pragma unroll
    for (int nt = 0; nt < 16; nt++) {
      bf16x8 bv = *(const bf16x8*)&b_s[nt * 16 + lc][quad * 8];
      acc[nt] = __builtin_amdgcn_mfma_f32_16x16x32_bf16(av, bv, acc[nt], 0, 0, 0);
    }
  }
  __syncthreads();  // b_s -> t2 reuse

  // ---- epilogue: transpose 16x32 chunks via LDS, packed coalesced stores ----
  float* t2 = t2base + w * 544;  // 16 rows x 34 cols fp32, per-wave private
  for (int ntp = 0; ntp < 8; ntp++) {
#pragma unroll
    for (int rr = 0; rr < 4; rr++) {
      t2[(quad * 4 + rr) * 34 + lc] = acc[2 * ntp][rr];
      t2[(quad * 4 + rr) * 34 + 16 + lc] = acc[2 * ntp + 1][rr];
    }
    __asm__ volatile("s_waitcnt lgkmcnt(0)" ::: "memory");
#pragma unroll
    for (int it = 0; it < 4; it++) {
      int item = lane + it * 64;
      int p = item & 15, rowi = item >> 4;
      float v0 = t2[rowi * 34 + 2 * p];
      float v1 = t2[rowi * 34 + 2 * p + 1];
      unsigned u = pk_bf16(v0, v1);
      int colpair = ntp * 16 + p;
      int rowg = row0 + w * 16 + rowi;
      if (rowg < N_) {
        if (colpair < 64) xlb[(size_t)rowg * 64 + colpair] = u;
        else xrb[(size_t)rowg * 64 + colpair - 64] = u;
      }
    }
    __asm__ volatile("s_waitcnt lgkmcnt(0)" ::: "memory");
  }
}

// ---------------- CSR aggregation (round-5 proven body) ----------------
__device__ __forceinline__ float ep8u(const uint4& u, const float* w) {
  float ep = up_lo(u.x) * w[0];
  ep = fmaf(up_hi(u.x), w[1], ep);
  ep = fmaf(up_lo(u.y), w[2], ep);
  ep = fmaf(up_hi(u.y), w[3], ep);
  ep = fmaf(up_lo(u.z), w[4], ep);
  ep = fmaf(up_hi(u.z), w[5], ep);
  ep = fmaf(up_lo(u.w), w[6], ep);
  ep = fmaf(up_hi(u.w), w[7], ep);
  return ep;
}

__global__ __launch_bounds__(256) void agg_csr(const int* __restrict__ eoff,
                                               const int* __restrict__ esrc,
                                               const unsigned* __restrict__ easb,
                                               const float* __restrict__ Wel,
                                               const float* __restrict__ attl,
                                               const unsigned* __restrict__ xlb,
                                               const unsigned* __restrict__ xrb,
                                               const float* __restrict__ cb,
                                               float* __restrict__ buf,
                                               float* __restrict__ ssum,
                                               float* __restrict__ ssq) {
  __shared__ float sA[256], sB[256], sC[256], sD[256];
  int t = threadIdx.x;
  int l = t & 63;
  int sub = t >> 6;
  int c0 = l * 2;
  float w0[8], w1[8];
#pragma unroll
  for (int k = 0; k < 8; k++) {
    float2 wv = *(const float2*)&Wel[k * H_ + c0];
    w0[k] = wv.x; w1[k] = wv.y;
  }
  float2 attv = *(const float2*)&attl[c0];
  float2 cbv = *(const float2*)&cb[c0];
  const uint4* eas4 = (const uint4*)easb;
  float a1_0 = 0.f, a1_1 = 0.f, a2_0 = 0.f, a2_1 = 0.f;
  for (int n = blockIdx.x * 4 + sub; n < N_; n += gridDim.x * 4) {
    unsigned xru = xrb[(size_t)n * 64 + l];
    float xr0 = up_lo(xru), xr1 = up_hi(xru);
    int e0 = eoff[n], e1 = eoff[n + 1];
    float acc0 = 0.f, acc1 = 0.f, den = 0.f;
    int j = e0;
    for (; j + 4 <= e1; j += 4) {
      int s0 = esrc[j], s1 = esrc[j + 1], s2 = esrc[j + 2], s3 = esrc[j + 3];
      uint4 u0 = eas4[j], u1 = eas4[j + 1], u2 = eas4[j + 2], u3 = eas4[j + 3];
      unsigned xu0 = xlb[(size_t)s0 * 64 + l];
      unsigned xu1 = xlb[(size_t)s1 * 64 + l];
      unsigned xu2 = xlb[(size_t)s2 * 64 + l];
      unsigned xu3 = xlb[(size_t)s3 * 64 + l];
      float x00 = up_lo(xu0), x01 = up_hi(xu0);
      float x10 = up_lo(xu1), x11 = up_hi(xu1);
      float x20 = up_lo(xu2), x21 = up_hi(xu2);
      float x30 = up_lo(xu3), x31 = up_hi(xu3);
      float m00 = x00 + xr0 + ep8u(u0, w0);
      float m01 = x01 + xr1 + ep8u(u0, w1);
      float m10 = x10 + xr0 + ep8u(u1, w0);
      float m11 = x11 + xr1 + ep8u(u1, w1);
      float m20 = x20 + xr0 + ep8u(u2, w0);
      float m21 = x21 + xr1 + ep8u(u2, w1);
      float m30 = x30 + xr0 + ep8u(u3, w0);
      float m31 = x31 + xr1 + ep8u(u3, w1);
      m00 = (m00 > 0.f) ? m00 : 0.2f * m00;
      m01 = (m01 > 0.f) ? m01 : 0.2f * m01;
      m10 = (m10 > 0.f) ? m10 : 0.2f * m10;
      m11 = (m11 > 0.f) ? m11 : 0.2f * m11;
      m20 = (m20 > 0.f) ? m20 : 0.2f * m20;
      m21 = (m21 > 0.f) ? m21 : 0.2f * m21;
      m30 = (m30 > 0.f) ? m30 : 0.2f * m30;
      m31 = (m31 > 0.f) ? m31 : 0.2f * m31;
      float p0 = fmaf(m00, attv.x, m01 * attv.y);
      float p1 = fmaf(m10, attv.x, m11 * attv.y);
      float p2 = fmaf(m20, attv.x, m21 * attv.y);
      float p3 = fmaf(m30, attv.x, m31 * attv.y);
#pragma unroll
      for (int off = 8; off > 0; off >>= 1) {
        p0 += __shfl_xor(p0, off, 64);
        p1 += __shfl_xor(p1, off, 64);
        p2 += __shfl_xor(p2, off, 64);
        p3 += __shfl_xor(p3, off, 64);
      }
      float e0v = __expf(p0), e1v = __expf(p1), e2v = __expf(p2), e3v = __expf(p3);
      acc0 = fmaf(e0v, x00, acc0); acc1 = fmaf(e0v, x01, acc1);
      acc0 = fmaf(e1v, x10, acc0); acc1 = fmaf(e1v, x11, acc1);
      acc0 = fmaf(e2v, x20, acc0); acc1 = fmaf(e2v, x21, acc1);
      acc0 = fmaf(e3v, x30, acc0); acc1 = fmaf(e3v, x31, acc1);
      den += (e0v + e1v) + (e2v + e3v);
    }
    for (; j < e1; j++) {
      int s0 = esrc[j];
      uint4 u0 = eas4[j];
      unsigned xu0 = xlb[(size_t)s0 * 64 + l];
      float x00 = up_lo(xu0), x01 = up_hi(xu0);
      float m00 = x00 + xr0 + ep8u(u0, w0);
      float m01 = x01 + xr1 + ep8u(u0, w1);
      m00 = (m00 > 0.f) ? m00 : 0.2f * m00;
      m01 = (m01 > 0.f) ? m01 : 0.2f * m01;
      float p0 = fmaf(m00, attv.x, m01 * attv.y);
#pragma unroll
      for (int off = 8; off > 0; off >>= 1) p0 += __shfl_xor(p0, off, 64);
      float e0v = __expf(p0);
      acc0 = fmaf(e0v, x00, acc0);
      acc1 = fmaf(e0v, x01, acc1);
      den += e0v;
    }
    float inv = 1.f / (den + 1e-16f);
    float h0 = acc0 * inv + cbv.x;
    float h1 = acc1 * inv + cbv.y;
    *(float2*)&buf[(size_t)n * H_ + c0] = make_float2(h0, h1);
    a1_0 += h0; a1_1 += h1;
    a2_0 = fmaf(h0, h0, a2_0); a2_1 = fmaf(h1, h1, a2_1);
  }
  sA[t] = a1_0; sB[t] = a1_1; sC[t] = a2_0; sD[t] = a2_1;
  __syncthreads();
  if (t < 64) {
    float r1 = sA[t] + sA[t + 64] + sA[t + 128] + sA[t + 192];
    float r2 = sB[t] + sB[t + 64] + sB[t + 128] + sB[t + 192];
    float r3 = sC[t] + sC[t + 64] + sC[t + 128] + sC[t + 192];
    float r4 = sD[t] + sD[t + 64] + sD[t + 128] + sD[t + 192];
    atomicAdd(&ssum[2 * t], r1);
    atomicAdd(&ssum[2 * t + 1], r2);
    atomicAdd(&ssq[2 * t], r3);
    atomicAdd(&ssq[2 * t + 1], r4);
  }
}

// ---------------- BN apply with inline finalize ----------------
__global__ __launch_bounds__(256) void apply_bn_relu(const float* __restrict__ y,
                                                     float* __restrict__ out,
                                                     const float* __restrict__ g,
                                                     const float* __restrict__ beta,
                                                     const float* __restrict__ ssum,
                                                     const float* __restrict__ ssq,
                                                     float rows_inv,
                                                     long total, int cmask) {
  long i = (long)blockIdx.x * 256 + threadIdx.x;
  if (i >= total) return;
  int c = (int)i & cmask;
  float m = ssum[c] * rows_inv;
  float rs = rsqrtf(ssq[c] * rows_inv - m * m + 1e-5f);
  float v = g[c] * (y[i] - m) * rs + beta[c];
  out[i] = fmaxf(v, 0.f);
}

// ---------------- pooling with fused layer-2 residual (inline BN finalize) ----
__global__ __launch_bounds__(128) void pool_residual(const int* __restrict__ goff,
                                                     const float* __restrict__ xn,
                                                     const float* __restrict__ buf,
                                                     const float* __restrict__ g,
                                                     const float* __restrict__ beta,
                                                     const float* __restrict__ ssum,
                                                     const float* __restrict__ ssq,
                                                     float rows_inv,
                                                     float* __restrict__ xg) {
  int gr = blockIdx.x;
  int t = threadIdx.x;
  int n0 = goff[gr], n1 = goff[gr + 1];
  float mm = ssum[t] * rows_inv;
  float rr = rsqrtf(ssq[t] * rows_inv - mm * mm + 1e-5f);
  float gg = g[t], bb = beta[t];
  float s = 0.f, mx = -INFINITY;
  for (int n = n0; n < n1; n++) {
    float w = gg * (buf[(size_t)n * H_ + t] - mm) * rr + bb;
    w = (w > 0.f) ? w : (__expf(w) - 1.f);
    float v = xn[(size_t)n * H_ + t] + w;
    s += v;
    mx = fmaxf(mx, v);
  }
  float c = (float)(n1 - n0);
  xg[gr * 384 + t] = s / fmaxf(c, 1.f);
  xg[gr * 384 + 128 + t] = (c > 0.f) ? mx : 0.f;
  xg[gr * 384 + 256 + t] = s;
}

// ---------------- MLP GEMMs (fused colstats) ----------------
template <int K, int COLS>
__global__ void mlp_gemm(const float* __restrict__ A, const float* __restrict__ W,
                         const float* __restrict__ b, float* __restrict__ Y, int rows,
                         float* __restrict__ ssum, float* __restrict__ ssq) {
  __shared__ float xs[8][K];
  int t = threadIdx.x;
  int row0 = blockIdx.x * 8;
  for (int i = t; i < 8 * K; i += COLS) {
    int r = i / K, k = i % K;
    int row = row0 + r;
    xs[r][k] = (row < rows) ? A[row * K + k] : 0.f;
  }
  __syncthreads();
  float acc[8];
#pragma unroll
  for (int r = 0; r < 8; r++) acc[r] = 0.f;
  for (int k = 0; k < K; k++) {
    float w = W[k * COLS + t];
#pragma unroll
    for (int r = 0; r < 8; r++) acc[r] = fmaf(xs[r][k], w, acc[r]);
  }
  float bb = b[t];
  float a1 = 0.f, a2 = 0.f;
#pragma unroll
  for (int r = 0; r < 8; r++) {
    int row = row0 + r;
    if (row < rows) {
      float v = acc[r] + bb;
      Y[row * COLS + t] = v;
      a1 += v;
      a2 = fmaf(v, v, a2);
    }
  }
  atomicAdd(&ssum[t], a1);
  atomicAdd(&ssq[t], a2);
}

// ---------------- head ----------------
__global__ __launch_bounds__(64) void head_kernel(const float* __restrict__ u,
                                                  const float* __restrict__ W,
                                                  const float* __restrict__ b,
                                                  float* __restrict__ out) {
  __shared__ float row[128];
  int g = blockIdx.x;
  int t = threadIdx.x;
  row[t] = u[g * 128 + t];
  row[t + 64] = u[g * 128 + 64 + t];
  __syncthreads();
  if (t < 12) {
    float acc = b[t];
    for (int k = 0; k < 128; k++) acc = fmaf(row[k], W[k * 12 + t], acc);
    out[g * 12 + t] = 1.f / (1.f + expf(-acc));
  }
}

// ---------------- launcher ----------------
extern "C" void kernel_launch(void* const* d_in, const int* in_sizes, int n_in, void* d_out,
                              int out_size, void* d_ws, size_t ws_size, hipStream_t stream) {
  (void)in_sizes; (void)n_in; (void)out_size; (void)ws_size;
  const float* x       = (const float*)d_in[0];
  const int*   ei      = (const int*)d_in[1];
  const float* ea      = (const float*)d_in[2];
  const int*   batch   = (const int*)d_in[3];
  const float* in_W    = (const float*)d_in[4];
  const float* in_b    = (const float*)d_in[5];
  const float* in_g    = (const float*)d_in[6];
  const float* in_beta = (const float*)d_in[7];
  const float* Wl      = (const float*)d_in[8];
  const float* Wr      = (const float*)d_in[9];
  const float* We      = (const float*)d_in[10];
  const float* att     = (const float*)d_in[11];
  const float* conv_b  = (const float*)d_in[12];
  const float* bn_g    = (const float*)d_in[13];
  const float* bn_b    = (const float*)d_in[14];
  const float* t1_W    = (const float*)d_in[15];
  const float* t1_b    = (const float*)d_in[16];
  const float* t1_g    = (const float*)d_in[17];
  const float* t1_beta = (const float*)d_in[18];
  const float* t2_W    = (const float*)d_in[19];
  const float* t2_b    = (const float*)d_in[20];
  const float* t2_g    = (const float*)d_in[21];
  const float* t2_beta = (const float*)d_in[22];
  const float* head_W  = (const float*)d_in[23];
  const float* head_b  = (const float*)d_in[24];
  float* out = (float*)d_out;

  float* p = (float*)d_ws;
  float* xn    = p; p += N_ * H_;
  float* buf   = p; p += N_ * H_;
  float* sstat = p; p += 6 * 512;   // 6 stages x (ssum 256 | ssq 256)
  float* xg    = p; p += G_ * 384;
  float* u1    = p; p += G_ * 256;
  float* u2    = p; p += G_ * 128;
  unsigned* up = (unsigned*)p;
  unsigned* xlb  = up; up += (size_t)N_ * 64;
  unsigned* xrb  = up; up += (size_t)N_ * 64;
  unsigned* easb = up; up += (size_t)E_ * 4;
  unsigned short* wpack = (unsigned short*)up; up += 3 * 32768 / 2;
  int* ip = (int*)up;
  int* deg    = ip; ip += N_;
  int* eoff   = ip; ip += N_ + 1;
  int* cursor = ip; ip += N_;
  int* goff   = ip; ip += G_ + 1;
  int* esrc   = ip; ip += E_;
  int* bsum   = ip; ip += 64;
  int* boff   = ip; ip += 64;

#define SSUM(s) (sstat + (s) * 512)
#define SSQ(s)  (sstat + (s) * 512 + 256)

  // ---- build CSR structures + pre-pack weights ----
  hipMemsetAsync(deg, 0, (size_t)N_ * sizeof(int), stream);
  hipMemsetAsync(sstat, 0, 6 * 512 * sizeof(float), stream);
  hist_kernel<<<1024, 256, 0, stream>>>(ei + E_, E_, deg);
  scan_local<<<49, 1024, 0, stream>>>(deg, eoff, bsum, N_);
  scan_bsum<<<1, 64, 0, stream>>>(bsum, boff, 49);
  scan_add<<<49, 1024, 0, stream>>>(eoff, boff, cursor, N_);
  edge_scatter<<<(E_ + 255) / 256, 256, 0, stream>>>(ei, ea, cursor, esrc, easb);
  goff_from_sorted<<<(N_ + 255) / 256, 256, 0, stream>>>(batch, goff);
  pack_weights<<<384, 256, 0, stream>>>(Wl, Wr, wpack);

  // ---- input layer (stats -> stage 0) ----
  in_gemm<<<(N_ + 31) / 32, 256, 0, stream>>>(x, in_W, in_b, buf, SSUM(0), SSQ(0));

  // ---- 3 GATv2 layers (conv stats of layer l -> stage l+1) ----
  const float rnInv = 1.f / N_;
  for (int l = 0; l < 3; l++) {
    if (l == 0) {
      gemm_mfma<1><<<782, 256, 0, stream>>>(xn, buf, in_g, in_beta, SSUM(0), SSQ(0), rnInv,
                                            wpack + (size_t)l * 32768, xlb, xrb);
    } else {
      gemm_mfma<2><<<782, 256, 0, stream>>>(xn, buf, bn_g + (l - 1) * H_, bn_b + (l - 1) * H_,
                                            SSUM(l), SSQ(l), rnInv,
                                            wpack + (size_t)l * 32768, xlb, xrb);
    }
    agg_csr<<<2048, 256, 0, stream>>>(eoff, esrc, easb, We + l * 8 * H_, att + l * H_,
                                      xlb, xrb, conv_b + l * H_, buf, SSUM(l + 1), SSQ(l + 1));
  }

  // ---- pooling with fused layer-2 residual (stage 3 stats) ----
  pool_residual<<<G_, 128, 0, stream>>>(goff, xn, buf, bn_g + 2 * H_, bn_b + 2 * H_,
                                        SSUM(3), SSQ(3), rnInv, xg);

  // ---- t1 (stats -> stage 4) ----
  const float rgInv = 1.f / G_;
  mlp_gemm<384, 256><<<G_ / 8, 256, 0, stream>>>(xg, t1_W, t1_b, u1, G_, SSUM(4), SSQ(4));
  apply_bn_relu<<<(G_ * 256 + 255) / 256, 256, 0, stream>>>(u1, u1, t1_g, t1_beta,
                                                            SSUM(4), SSQ(4), rgInv,
                                                            (long)G_ * 256, 255);

  // ---- t2 (stats -> stage 5) ----
  mlp_gemm<256, 128><<<G_ / 8, 128, 0, stream>>>(u1, t2_W, t2_b, u2, G_, SSUM(5), SSQ(5));
  apply_bn_relu<<<(G_ * 128 + 255) / 256, 256, 0, stream>>>(u2, u2, t2_g, t2_beta,
                                                            SSUM(5), SSQ(5), rgInv,
                                                            (long)G_ * 128, 127);

  // ---- head ----
  head_kernel<<<G_, 64, 0, stream>>>(u2, head_W, head_b, out);
#undef SSUM
#undef SSQ
}